// Round 2
// baseline (5878.513 us; speedup 1.0000x reference)
//
#include <hip/hip_runtime.h>
#include <hip/hip_bf16.h>

typedef long long ll;
typedef unsigned int uint;
typedef unsigned short ushort;

// Problem constants
// B=2, L=4096, D_MODEL=2048, D_INNER=4096, D_STATE=128, N_HEADS=64, D_HEAD=64
// CONV_DIM=4352, D_IN_PROJ=8512, CHUNK=256, chunks total = 32
//
// Workspace budget (bf16 bulk intermediates, fp32 compute): 252,706,816 B = 241 MiB
//   zx   bf16 [8192][8512]  @ 0          (z | xBC_raw -> y | dt_raw)
//   xbc  bf16 [8192][4352]  @ 139,460,608
//   st   bf16 [32][64][64][128] @ 210,763,776
//   CB   bf16 [32][256][256] @ 244,318,208
//   dt_sp f32 [8192][64]    @ 248,512,512
//   dAcs  f32 [8192][64]    @ 250,609,664

__device__ __forceinline__ float silu_f(float x) { return x / (1.0f + expf(-x)); }
__device__ __forceinline__ float softplus_f(float x) {
  return x > 20.0f ? x : log1pf(expf(x));
}
__device__ __forceinline__ float b2f(ushort u) {
  return __uint_as_float(((uint)u) << 16);
}
__device__ __forceinline__ ushort f2b(float f) {
  uint x = __float_as_uint(f);
  return (ushort)((x + 0x7FFFu + ((x >> 16) & 1u)) >> 16);
}
__device__ __forceinline__ uint pk2(float a, float b) {
  return (uint)f2b(a) | ((uint)f2b(b) << 16);
}
__device__ __forceinline__ void unpack8(uint4 u, float* f) {
  f[0] = b2f((ushort)(u.x & 0xffff)); f[1] = b2f((ushort)(u.x >> 16));
  f[2] = b2f((ushort)(u.y & 0xffff)); f[3] = b2f((ushort)(u.y >> 16));
  f[4] = b2f((ushort)(u.z & 0xffff)); f[5] = b2f((ushort)(u.z >> 16));
  f[6] = b2f((ushort)(u.w & 0xffff)); f[7] = b2f((ushort)(u.w >> 16));
}

// ---------------- GEMM: C[M,N] = A[M,K] @ B[N,K]^T (both K-major) ----------
// fp32 compute; A/B/C each independently fp32 or bf16 storage.
// 128x128 tile, BK=16, 256 threads, 8x8 per thread. M%128==0, K%16==0.
// N guarded (B-row loads clamped, stores predicated).
template <int ABF, int BBF, int CBF>
__global__ __launch_bounds__(256) void gemm_nt(
    const void* __restrict__ Av, const void* __restrict__ Bv, void* __restrict__ Cv,
    int M, int N, int K, int lda, int ldb, int ldc,
    ll batchA, ll batchB, ll batchC)
{
  __shared__ float As[16][128];
  __shared__ float Bs[16][128];
  const int t = threadIdx.x;
  const int bm = blockIdx.y * 128;
  const int bn = blockIdx.x * 128;
  const int tx = t & 15, ty = t >> 4;
  const int srow = t >> 1;          // 0..127
  const int sk = (t & 1) << 3;      // 0 or 8
  float acc[8][8] = {};

  const ll arow = (ll)blockIdx.z * batchA + (ll)(bm + srow) * lda;
  int brow_i = bn + srow; if (brow_i > N - 1) brow_i = N - 1;  // clamp, store-guarded
  const ll brow = (ll)blockIdx.z * batchB + (ll)brow_i * ldb;
  const ll zc = (ll)blockIdx.z * batchC;

  for (int k0 = 0; k0 < K; k0 += 16) {
    __syncthreads();
    float av[8], bv[8];
    if constexpr (ABF) {
      uint4 ua = *(const uint4*)((const ushort*)Av + arow + k0 + sk);
      unpack8(ua, av);
    } else {
      const float* p = (const float*)Av + arow + k0 + sk;
      float4 x0 = *(const float4*)p, x1 = *(const float4*)(p + 4);
      av[0] = x0.x; av[1] = x0.y; av[2] = x0.z; av[3] = x0.w;
      av[4] = x1.x; av[5] = x1.y; av[6] = x1.z; av[7] = x1.w;
    }
    if constexpr (BBF) {
      uint4 ub = *(const uint4*)((const ushort*)Bv + brow + k0 + sk);
      unpack8(ub, bv);
    } else {
      const float* p = (const float*)Bv + brow + k0 + sk;
      float4 x0 = *(const float4*)p, x1 = *(const float4*)(p + 4);
      bv[0] = x0.x; bv[1] = x0.y; bv[2] = x0.z; bv[3] = x0.w;
      bv[4] = x1.x; bv[5] = x1.y; bv[6] = x1.z; bv[7] = x1.w;
    }
#pragma unroll
    for (int j = 0; j < 8; ++j) { As[sk + j][srow] = av[j]; Bs[sk + j][srow] = bv[j]; }
    __syncthreads();
#pragma unroll
    for (int k = 0; k < 16; ++k) {
      float a[8], b[8];
      *(float4*)&a[0] = *(const float4*)&As[k][ty * 4];
      *(float4*)&a[4] = *(const float4*)&As[k][64 + ty * 4];
      *(float4*)&b[0] = *(const float4*)&Bs[k][tx * 4];
      *(float4*)&b[4] = *(const float4*)&Bs[k][64 + tx * 4];
#pragma unroll
      for (int i = 0; i < 8; ++i)
#pragma unroll
        for (int j = 0; j < 8; ++j)
          acc[i][j] = fmaf(a[i], b[j], acc[i][j]);
    }
  }
#pragma unroll
  for (int i = 0; i < 8; ++i) {
    int r = bm + (i < 4 ? ty * 4 + i : 64 + ty * 4 + (i - 4));
    ll rb = zc + (ll)r * ldc;
    int c0 = bn + tx * 4;
    int c1 = bn + 64 + tx * 4;
    if constexpr (CBF) {
      if (c0 < N) {
        ushort4 s; s.x = f2b(acc[i][0]); s.y = f2b(acc[i][1]);
        s.z = f2b(acc[i][2]); s.w = f2b(acc[i][3]);
        *(ushort4*)((ushort*)Cv + rb + c0) = s;
      }
      if (c1 < N) {
        ushort4 s; s.x = f2b(acc[i][4]); s.y = f2b(acc[i][5]);
        s.z = f2b(acc[i][6]); s.w = f2b(acc[i][7]);
        *(ushort4*)((ushort*)Cv + rb + c1) = s;
      }
    } else {
      if (c0 < N)
        *(float4*)((float*)Cv + rb + c0) =
            make_float4(acc[i][0], acc[i][1], acc[i][2], acc[i][3]);
      if (c1 < N)
        *(float4*)((float*)Cv + rb + c1) =
            make_float4(acc[i][4], acc[i][5], acc[i][6], acc[i][7]);
    }
  }
}

// ---------------- depthwise conv (width 4, causal) + bias + SiLU -----------
// reads zx cols [4096, 8448) (bf16), writes xbc[B*L][4352] (bf16)
__global__ __launch_bounds__(256) void conv_silu(
    const ushort* __restrict__ zx, const float* __restrict__ cw,
    const float* __restrict__ cbias, ushort* __restrict__ out)
{
  ll tid = (ll)blockIdx.x * 256 + threadIdx.x;  // one per (b,l,ch4); total 2*4096*1088
  int ch4 = (int)(tid % 1088) << 2;
  ll bl = tid / 1088;
  int l = (int)(bl & 4095);
  ll rowbase = bl - l;  // b*4096
  float4 acc = *(const float4*)&cbias[ch4];
  float4 w0 = *(const float4*)&cw[(ch4 + 0) * 4];
  float4 w1 = *(const float4*)&cw[(ch4 + 1) * 4];
  float4 w2 = *(const float4*)&cw[(ch4 + 2) * 4];
  float4 w3 = *(const float4*)&cw[(ch4 + 3) * 4];
#define TAP(W, COMP)                                                               \
  { int llx = l + (W) - 3;                                                         \
    if (llx >= 0) {                                                                \
      ushort4 xv = *(const ushort4*)&zx[(rowbase + llx) * 8512 + 4096 + ch4];      \
      acc.x = fmaf(b2f(xv.x), w0.COMP, acc.x);                                     \
      acc.y = fmaf(b2f(xv.y), w1.COMP, acc.y);                                     \
      acc.z = fmaf(b2f(xv.z), w2.COMP, acc.z);                                     \
      acc.w = fmaf(b2f(xv.w), w3.COMP, acc.w); } }
  TAP(0, x) TAP(1, y) TAP(2, z) TAP(3, w)
#undef TAP
  ushort4 o;
  o.x = f2b(silu_f(acc.x)); o.y = f2b(silu_f(acc.y));
  o.z = f2b(silu_f(acc.z)); o.w = f2b(silu_f(acc.w));
  *(ushort4*)&out[bl * 4352 + ch4] = o;
}

// ---------------- dt softplus + per-chunk cumsum of dt*A -------------------
__global__ __launch_bounds__(256) void dt_cumsum(
    const ushort* __restrict__ zx, const float* __restrict__ dt_bias,
    const float* __restrict__ A_log, float* __restrict__ dt_sp,
    float* __restrict__ dA)
{
  __shared__ float sdt[256][64];  // 64 KiB
  const int bc = blockIdx.x;
  const int t = threadIdx.x;
#pragma unroll
  for (int q = 0; q < 16; ++q) {
    int ff = q * 256 + t;           // 4-elem slot, 4096 total
    int i = ff >> 4;
    int h4 = (ff & 15) << 2;
    ushort4 v4 = *(const ushort4*)&zx[((ll)bc * 256 + i) * 8512 + 8448 + h4];
    float4 bb = *(const float4*)&dt_bias[h4];
    float4 v;
    v.x = softplus_f(b2f(v4.x) + bb.x); v.y = softplus_f(b2f(v4.y) + bb.y);
    v.z = softplus_f(b2f(v4.z) + bb.z); v.w = softplus_f(b2f(v4.w) + bb.w);
    *(float4*)&dt_sp[((ll)bc * 256 + i) * 64 + h4] = v;
    *(float4*)&sdt[i][h4] = v;
  }
  __syncthreads();
  if (t < 64) {
    const int h = t;
    const float Ah = -expf(A_log[h]);
    float run = 0.0f;
    for (int i = 0; i < 256; ++i) {
      run = fmaf(sdt[i][h], Ah, run);
      dA[((ll)bc * 256 + i) * 64 + h] = run;
    }
  }
}

// ---------------- per-chunk end states: st[bc][h][p][n] (bf16) -------------
__global__ __launch_bounds__(256) void states_kernel(
    const ushort* __restrict__ xbc, const float* __restrict__ dt_sp,
    const float* __restrict__ dA, ushort* __restrict__ st)
{
  const int bc = blockIdx.x, h = blockIdx.y;
  const int t = threadIdx.x;
  __shared__ float sA[256], sdt[256];
  __shared__ float sxw[64][68];
  __shared__ float sB[64][132];
  sA[t]  = dA[((ll)bc * 256 + t) * 64 + h];
  sdt[t] = dt_sp[((ll)bc * 256 + t) * 64 + h];
  __syncthreads();
  const float dAlast = sA[255];
  const int pt = t & 15, nt = t >> 4;
  float acc[4][8] = {};

  for (int s0 = 0; s0 < 256; s0 += 64) {
    __syncthreads();
#pragma unroll
    for (int q = 0; q < 4; ++q) {   // stage x * (decay_last * dt): 64x64
      int ff = q * 256 + t;
      int s = ff >> 4, p4 = (ff & 15) << 2;
      float w = expf(dAlast - sA[s0 + s]) * sdt[s0 + s];
      ushort4 xv = *(const ushort4*)&xbc[((ll)bc * 256 + s0 + s) * 4352 + h * 64 + p4];
      float4 f;
      f.x = b2f(xv.x) * w; f.y = b2f(xv.y) * w;
      f.z = b2f(xv.z) * w; f.w = b2f(xv.w) * w;
      *(float4*)&sxw[s][p4] = f;
    }
#pragma unroll
    for (int q = 0; q < 8; ++q) {   // stage B: 64x128
      int ff = q * 256 + t;
      int s = ff >> 5, n4 = (ff & 31) << 2;
      ushort4 bv = *(const ushort4*)&xbc[((ll)bc * 256 + s0 + s) * 4352 + 4096 + n4];
      float4 f;
      f.x = b2f(bv.x); f.y = b2f(bv.y); f.z = b2f(bv.z); f.w = b2f(bv.w);
      *(float4*)&sB[s][n4] = f;
    }
    __syncthreads();
#pragma unroll 8
    for (int s = 0; s < 64; ++s) {
      float4 xv = *(const float4*)&sxw[s][pt * 4];
      float4 b0 = *(const float4*)&sB[s][nt * 8];
      float4 b1 = *(const float4*)&sB[s][nt * 8 + 4];
      float xa[4] = {xv.x, xv.y, xv.z, xv.w};
      float bb[8] = {b0.x, b0.y, b0.z, b0.w, b1.x, b1.y, b1.z, b1.w};
#pragma unroll
      for (int i = 0; i < 4; ++i)
#pragma unroll
        for (int j = 0; j < 8; ++j)
          acc[i][j] = fmaf(xa[i], bb[j], acc[i][j]);
    }
  }
  ll base = ((ll)bc * 64 + h) * 8192;
#pragma unroll
  for (int i = 0; i < 4; ++i) {
    int p = pt * 4 + i;
    ushort4 o0; o0.x = f2b(acc[i][0]); o0.y = f2b(acc[i][1]);
    o0.z = f2b(acc[i][2]); o0.w = f2b(acc[i][3]);
    ushort4 o1; o1.x = f2b(acc[i][4]); o1.y = f2b(acc[i][5]);
    o1.z = f2b(acc[i][6]); o1.w = f2b(acc[i][7]);
    *(ushort4*)&st[base + p * 128 + nt * 8] = o0;
    *(ushort4*)&st[base + p * 128 + nt * 8 + 4] = o1;
  }
}

// ---------------- inter-chunk scan, in place: st[c] := carry-before-chunk-c
__global__ __launch_bounds__(256) void scan_kernel(
    ushort* __restrict__ st, const float* __restrict__ dA)
{
  ll tid = (ll)blockIdx.x * 256 + threadIdx.x;  // 2*64*64*128 = 1,048,576
  int n = (int)(tid & 127);
  int p = (int)((tid >> 7) & 63);
  int h = (int)((tid >> 13) & 63);
  int b = (int)(tid >> 19);
  float s = 0.0f;  // carry stays fp32 in-register
#pragma unroll
  for (int c = 0; c < 16; ++c) {
    int bc = b * 16 + c;
    float dec = expf(dA[((ll)bc * 256 + 255) * 64 + h]);
    ll idx = ((ll)bc * 64 + h) * 8192 + p * 128 + n;
    float tmp = b2f(st[idx]);
    st[idx] = f2b(s);        // prev (state before this chunk)
    s = fmaf(s, dec, tmp);   // carry
  }
}

// ---------------- y = y_diag + y_off + Dp*x -> zx cols [4096,8192) (bf16) --
__global__ __launch_bounds__(256) void ssm_y(
    const ushort* __restrict__ xbc, const float* __restrict__ dt_sp,
    const float* __restrict__ dA, const ushort* __restrict__ CB,
    const ushort* __restrict__ prev, const float* __restrict__ Dp,
    ushort* __restrict__ zx)
{
  const int bc = blockIdx.x, h = blockIdx.y;
  const int t = threadIdx.x;
  const int pt = t & 3, it = t >> 2;  // rows i = it*4+{0..3}; cols p = pt*16+{0..15}
  const int p0 = pt * 16;
  __shared__ float sm[13120];
  float* sA  = sm;         // 256
  float* sdt = sm + 256;   // 256
  float* R   = sm + 512;
  float* sx  = R;          // phase1: [32][68]  = 2176
  float* sCB = R + 2176;   // phase1: [256][33] = 8448
  float* spv = R;          // phase2: [64][129] = 8256
  float* sCt = R + 8256;   // phase2: [256][17] = 4352

  sA[t]  = dA[((ll)bc * 256 + t) * 64 + h];
  sdt[t] = dt_sp[((ll)bc * 256 + t) * 64 + h];
  __syncthreads();
  float sAi[4], ei[4];
#pragma unroll
  for (int i = 0; i < 4; ++i) {
    sAi[i] = sA[it * 4 + i];
    ei[i] = expf(sAi[i]);
  }
  float acc[4][16] = {};

  // ---- phase 1: y_diag (masked M @ x) ----
  for (int jt = 0; jt < 8; ++jt) {
    __syncthreads();
#pragma unroll
    for (int q = 0; q < 2; ++q) {          // stage x j-tile 32x64
      int ff = q * 256 + t;
      int jj = ff >> 4, p4 = (ff & 15) << 2;
      ushort4 xv = *(const ushort4*)&xbc[((ll)bc * 256 + jt * 32 + jj) * 4352 + h * 64 + p4];
      float4 f;
      f.x = b2f(xv.x); f.y = b2f(xv.y); f.z = b2f(xv.z); f.w = b2f(xv.w);
      *(float4*)&sx[jj * 68 + p4] = f;
    }
#pragma unroll
    for (int q = 0; q < 8; ++q) {          // stage CB 256 x 32
      int ff = q * 256 + t;
      int i = ff >> 3, j4 = (ff & 7) << 2;
      ushort4 cv = *(const ushort4*)&CB[((ll)bc * 256 + i) * 256 + jt * 32 + j4];
      sCB[i * 33 + j4 + 0] = b2f(cv.x); sCB[i * 33 + j4 + 1] = b2f(cv.y);
      sCB[i * 33 + j4 + 2] = b2f(cv.z); sCB[i * 33 + j4 + 3] = b2f(cv.w);
    }
    __syncthreads();
    if (jt * 32 <= it * 4 + 3) {           // whole-tile triangular skip
      for (int jj = 0; jj < 32; ++jj) {
        int j = jt * 32 + jj;
        float dAj = sA[j];
        float dtj = sdt[j];
        float m[4];
#pragma unroll
        for (int i = 0; i < 4; ++i) {
          int irow = it * 4 + i;
          m[i] = (j <= irow) ? sCB[irow * 33 + jj] * expf(sAi[i] - dAj) * dtj : 0.0f;
        }
        float xv[16];
#pragma unroll
        for (int qq = 0; qq < 4; ++qq)
          *(float4*)&xv[qq * 4] = *(const float4*)&sx[jj * 68 + p0 + qq * 4];
#pragma unroll
        for (int i = 0; i < 4; ++i)
#pragma unroll
          for (int q = 0; q < 16; ++q)
            acc[i][q] = fmaf(m[i], xv[q], acc[i][q]);
      }
    }
  }

  // ---- phase 2: y_off = exp(dA_i) * C @ prev^T ----
  __syncthreads();
#pragma unroll
  for (int q = 0; q < 8; ++q) {            // stage prev[p][n] 64x128
    int ff = q * 256 + t;
    int p = ff >> 5, n4 = (ff & 31) << 2;
    ushort4 pv = *(const ushort4*)&prev[((ll)bc * 64 + h) * 8192 + p * 128 + n4];
    spv[p * 129 + n4 + 0] = b2f(pv.x); spv[p * 129 + n4 + 1] = b2f(pv.y);
    spv[p * 129 + n4 + 2] = b2f(pv.z); spv[p * 129 + n4 + 3] = b2f(pv.w);
  }
  for (int n0 = 0; n0 < 128; n0 += 16) {
    __syncthreads();
#pragma unroll
    for (int q = 0; q < 4; ++q) {          // stage C n-tile 256x16
      int ff = q * 256 + t;
      int i = ff >> 2, n4 = (ff & 3) << 2;
      ushort4 cv = *(const ushort4*)&xbc[((ll)bc * 256 + i) * 4352 + 4224 + n0 + n4];
      sCt[i * 17 + n4 + 0] = b2f(cv.x); sCt[i * 17 + n4 + 1] = b2f(cv.y);
      sCt[i * 17 + n4 + 2] = b2f(cv.z); sCt[i * 17 + n4 + 3] = b2f(cv.w);
    }
    __syncthreads();
    for (int nn = 0; nn < 16; ++nn) {
      int n = n0 + nn;
      float cc[4];
#pragma unroll
      for (int i = 0; i < 4; ++i)
        cc[i] = sCt[(it * 4 + i) * 17 + nn] * ei[i];
      float pv[16];
#pragma unroll
      for (int q = 0; q < 16; ++q)
        pv[q] = spv[(p0 + q) * 129 + n];
#pragma unroll
      for (int i = 0; i < 4; ++i)
#pragma unroll
        for (int q = 0; q < 16; ++q)
          acc[i][q] = fmaf(cc[i], pv[q], acc[i][q]);
    }
  }

  // ---- epilogue: + Dp*x, store bf16 into zx cols [4096+h*64+p] ----
  float dph = Dp[h];
#pragma unroll
  for (int i = 0; i < 4; ++i) {
    ll row = (ll)bc * 256 + it * 4 + i;
#pragma unroll
    for (int qq = 0; qq < 4; ++qq) {
      ushort4 xv = *(const ushort4*)&xbc[row * 4352 + h * 64 + p0 + qq * 4];
      ushort4 o;
      o.x = f2b(acc[i][qq * 4 + 0] + dph * b2f(xv.x));
      o.y = f2b(acc[i][qq * 4 + 1] + dph * b2f(xv.y));
      o.z = f2b(acc[i][qq * 4 + 2] + dph * b2f(xv.z));
      o.w = f2b(acc[i][qq * 4 + 3] + dph * b2f(xv.w));
      *(ushort4*)&zx[row * 8512 + 4096 + h * 64 + p0 + qq * 4] = o;
    }
  }
}

// ---------------- gated RMSNorm, in place on zx cols [4096,8192) -----------
__global__ __launch_bounds__(256) void gated_rmsnorm(
    ushort* __restrict__ zx, const float* __restrict__ norm_w)
{
  const ll row = blockIdx.x;
  ushort* zrow = zx + row * 8512;
  ushort* yrow = zrow + 4096;
  const int t = threadIdx.x;
  float g[16];
  float ss = 0.0f;
#pragma unroll
  for (int q = 0; q < 2; ++q) {
    int d = q * 2048 + t * 8;
    uint4 yv = *(const uint4*)&yrow[d];
    uint4 zv = *(const uint4*)&zrow[d];
    float yf[8], zf[8];
    unpack8(yv, yf);
    unpack8(zv, zf);
#pragma unroll
    for (int j = 0; j < 8; ++j) {
      float gv = yf[j] * silu_f(zf[j]);
      g[q * 8 + j] = gv;
      ss += gv * gv;
    }
  }
#pragma unroll
  for (int o = 32; o > 0; o >>= 1) ss += __shfl_xor(ss, o);
  __shared__ float red[4];
  if ((t & 63) == 0) red[t >> 6] = ss;
  __syncthreads();
  ss = red[0] + red[1] + red[2] + red[3];
  float scale = rsqrtf(ss * (1.0f / 4096.0f) + 1e-5f);
#pragma unroll
  for (int q = 0; q < 2; ++q) {
    int d = q * 2048 + t * 8;
    float4 w0 = *(const float4*)&norm_w[d];
    float4 w1 = *(const float4*)&norm_w[d + 4];
    uint4 o;
    o.x = pk2(g[q * 8 + 0] * scale * w0.x, g[q * 8 + 1] * scale * w0.y);
    o.y = pk2(g[q * 8 + 2] * scale * w0.z, g[q * 8 + 3] * scale * w0.w);
    o.z = pk2(g[q * 8 + 4] * scale * w1.x, g[q * 8 + 5] * scale * w1.y);
    o.w = pk2(g[q * 8 + 6] * scale * w1.z, g[q * 8 + 7] * scale * w1.w);
    *(uint4*)&yrow[d] = o;
  }
}

extern "C" void kernel_launch(void* const* d_in, const int* in_sizes, int n_in,
                              void* d_out, int out_size, void* d_ws, size_t ws_size,
                              hipStream_t stream) {
  const float* u       = (const float*)d_in[0];
  const float* W_in    = (const float*)d_in[1];
  const float* conv_w  = (const float*)d_in[2];
  const float* conv_b  = (const float*)d_in[3];
  const float* dt_bias = (const float*)d_in[4];
  const float* A_log   = (const float*)d_in[5];
  const float* Dp      = (const float*)d_in[6];
  const float* norm_w  = (const float*)d_in[7];
  const float* W_out   = (const float*)d_in[8];
  float* out = (float*)d_out;

  char* wsb = (char*)d_ws;
  ushort* zx    = (ushort*)wsb;                       // 139,460,608 B
  ushort* xbc   = (ushort*)(wsb + 139460608LL);       //  71,303,168 B
  ushort* st    = (ushort*)(wsb + 210763776LL);       //  33,554,432 B
  ushort* CBb   = (ushort*)(wsb + 244318208LL);       //   4,194,304 B
  float*  dt_sp = (float*)(wsb + 248512512LL);        //   2,097,152 B
  float*  dAcs  = (float*)(wsb + 250609664LL);        //   2,097,152 B
  // total 252,706,816 B

  // 1. in_proj: zx = u @ W_in^T   [8192 x 8512, K=2048]  (f32,f32 -> bf16)
  gemm_nt<0, 0, 1><<<dim3(67, 64, 1), 256, 0, stream>>>(
      u, W_in, zx, 8192, 8512, 2048, 2048, 2048, 8512, 0, 0, 0);
  // 2. causal conv + SiLU
  conv_silu<<<34816, 256, 0, stream>>>(zx, conv_w, conv_b, xbc);
  // 3. dt softplus + chunk cumsum
  dt_cumsum<<<32, 256, 0, stream>>>(zx, dt_bias, A_log, dt_sp, dAcs);
  // 4. CB[bc][i][j] = C_i . B_j  (batched 256x256, K=128)  (bf16 -> bf16)
  gemm_nt<1, 1, 1><<<dim3(2, 2, 32), 256, 0, stream>>>(
      xbc + 4224, xbc + 4096, CBb, 256, 256, 128,
      4352, 4352, 256, 256LL * 4352, 256LL * 4352, 65536LL);
  // 5. per-chunk end states
  states_kernel<<<dim3(32, 64), 256, 0, stream>>>(xbc, dt_sp, dAcs, st);
  // 6. inter-chunk scan (in place: st becomes prev)
  scan_kernel<<<4096, 256, 0, stream>>>(st, dAcs);
  // 7. y_diag + y_off + Dp*x  -> zx cols [4096,8192)
  ssm_y<<<dim3(32, 64), 256, 0, stream>>>(xbc, dt_sp, dAcs, CBb, st, Dp, zx);
  // 8. gated RMSNorm (in place)
  gated_rmsnorm<<<8192, 256, 0, stream>>>(zx, norm_w);
  // 9. out_proj: out = y @ W_out^T  [8192 x 2048, K=4096]  (bf16,f32 -> f32)
  gemm_nt<1, 0, 0><<<dim3(16, 64, 1), 256, 0, stream>>>(
      zx + 4096, W_out, out, 8192, 2048, 4096, 8512, 4096, 2048, 0, 0, 0);
}

// Round 3
// 1793.327 us; speedup vs baseline: 3.2780x; 3.2780x over previous
//
#include <hip/hip_runtime.h>
#include <hip/hip_bf16.h>

typedef long long ll;
typedef unsigned int uint;
typedef unsigned short ushort;

typedef __bf16 bf16x8 __attribute__((ext_vector_type(8)));
typedef float f32x4 __attribute__((ext_vector_type(4)));

// Problem constants
// B=2, L=4096, D_MODEL=2048, D_INNER=4096, D_STATE=128, N_HEADS=64, D_HEAD=64
// CONV_DIM=4352, D_IN_PROJ=8512 (padded to 8576 = 67*128), CHUNK=256, 32 chunks
//
// Workspace (242 MiB):
//   zx    bf16 [8192][8576]      @ 0            (z | xBC_raw->y | dt_raw | pad)
//   xbc   bf16 [8192][4352]      @ 140,509,184  (aliased early: u_bf, Win_bf)
//   st    bf16 [32][64][64][128] @ 211,812,352  (aliased late: Wout_bf)
//   CB    bf16 [32][256][256]    @ 245,366,784
//   dt_sp f32  [8192][64]        @ 249,561,088
//   dAcs  f32  [8192][64]        @ 251,658,240   (end 253,755,392)

__device__ __forceinline__ float silu_f(float x) { return x / (1.0f + expf(-x)); }
__device__ __forceinline__ float softplus_f(float x) {
  return x > 20.0f ? x : log1pf(expf(x));
}
__device__ __forceinline__ float b2f(ushort u) {
  return __uint_as_float(((uint)u) << 16);
}
__device__ __forceinline__ ushort f2b(float f) {
  uint x = __float_as_uint(f);
  return (ushort)((x + 0x7FFFu + ((x >> 16) & 1u)) >> 16);
}
__device__ __forceinline__ uint pk2(float a, float b) {
  return (uint)f2b(a) | ((uint)f2b(b) << 16);
}
__device__ __forceinline__ void unpack8(uint4 u, float* f) {
  f[0] = b2f((ushort)(u.x & 0xffff)); f[1] = b2f((ushort)(u.x >> 16));
  f[2] = b2f((ushort)(u.y & 0xffff)); f[3] = b2f((ushort)(u.y >> 16));
  f[4] = b2f((ushort)(u.z & 0xffff)); f[5] = b2f((ushort)(u.z >> 16));
  f[6] = b2f((ushort)(u.w & 0xffff)); f[7] = b2f((ushort)(u.w >> 16));
}

#define GLDS16(g, l)                                                     \
  __builtin_amdgcn_global_load_lds(                                      \
      (const __attribute__((address_space(1))) void*)(g),                \
      (__attribute__((address_space(3))) void*)(l), 16, 0, 0)

// ---------------- f32 -> bf16 convert (8 elems/thread) ---------------------
__global__ __launch_bounds__(256) void f32_to_bf16(
    const float* __restrict__ in, ushort* __restrict__ out, ll n)
{
  ll i = ((ll)blockIdx.x * 256 + threadIdx.x) * 8;
  if (i + 8 > n) return;
  float4 a = *(const float4*)&in[i];
  float4 b = *(const float4*)&in[i + 4];
  ushort4 o0; o0.x = f2b(a.x); o0.y = f2b(a.y); o0.z = f2b(a.z); o0.w = f2b(a.w);
  ushort4 o1; o1.x = f2b(b.x); o1.y = f2b(b.y); o1.z = f2b(b.z); o1.w = f2b(b.w);
  *(ushort4*)&out[i] = o0;
  *(ushort4*)&out[i + 4] = o1;
}

// ---------------- bf16 MFMA GEMM: C[M,N] = A[M,K] @ B[N,K]^T ---------------
// m97 structure: 128x128 tile, BK=32, 256 thr = 4 waves (2x2), 64x64/wave,
// global_load_lds width 16, mfma_f32_16x16x32_bf16, fp32 accum.
// M%128==0, K%32==0, grid.x*128 columns allocated in C (Nreal only load-clamped).
template <int CBF>  // 1: bf16 C, 0: f32 C
__global__ __launch_bounds__(256) void gemm_mfma(
    const ushort* __restrict__ A, const ushort* __restrict__ B, void* __restrict__ C,
    int Nreal, int K, int lda, int ldb, int ldc)
{
  __shared__ ushort As[128 * 32];
  __shared__ ushort Bs[128 * 32];
  const int t = threadIdx.x;
  const int lane = t & 63, w = t >> 6;
  const int wr = w >> 1, wc = w & 1;
  const int bm = blockIdx.y * 128, bn = blockIdx.x * 128;

  // staging addresses: issue q covers rows q*64..q*64+63; thread t -> row t/4, k (t%4)*8
  const int srow = t >> 2, skc = (t & 3) << 3;
  const ll a0 = (ll)(bm + srow) * lda + skc;
  const ll a1 = (ll)(bm + 64 + srow) * lda + skc;
  int br0 = bn + srow;      if (br0 >= Nreal) br0 = Nreal - 1;
  int br1 = bn + 64 + srow; if (br1 >= Nreal) br1 = Nreal - 1;
  const ll b0 = (ll)br0 * ldb + skc;
  const ll b1 = (ll)br1 * ldb + skc;
  ushort* lA0 = As + t * 8;        ushort* lA1 = As + 2048 + t * 8;
  ushort* lB0 = Bs + t * 8;        ushort* lB1 = Bs + 2048 + t * 8;

  f32x4 acc[4][4];
#pragma unroll
  for (int m = 0; m < 4; ++m)
#pragma unroll
    for (int n = 0; n < 4; ++n) acc[m][n] = (f32x4){0.f, 0.f, 0.f, 0.f};

  const int fr = lane & 15;          // fragment row within 16
  const int fk = (lane >> 4) << 3;   // k offset 0/8/16/24

  for (int k0 = 0; k0 < K; k0 += 32) {
    GLDS16(A + a0 + k0, lA0);
    GLDS16(A + a1 + k0, lA1);
    GLDS16(B + b0 + k0, lB0);
    GLDS16(B + b1 + k0, lB1);
    __syncthreads();
    bf16x8 af[4], bf[4];
#pragma unroll
    for (int m = 0; m < 4; ++m)
      af[m] = *(const bf16x8*)&As[(wr * 64 + m * 16 + fr) * 32 + fk];
#pragma unroll
    for (int n = 0; n < 4; ++n)
      bf[n] = *(const bf16x8*)&Bs[(wc * 64 + n * 16 + fr) * 32 + fk];
#pragma unroll
    for (int m = 0; m < 4; ++m)
#pragma unroll
      for (int n = 0; n < 4; ++n)
        acc[m][n] = __builtin_amdgcn_mfma_f32_16x16x32_bf16(af[m], bf[n], acc[m][n], 0, 0, 0);
    __syncthreads();
  }

  // C/D layout (m89-verified): col = lane&15, row = (lane>>4)*4 + reg
  const int cr = (lane >> 4) << 2, cc = lane & 15;
#pragma unroll
  for (int m = 0; m < 4; ++m) {
#pragma unroll
    for (int n = 0; n < 4; ++n) {
#pragma unroll
      for (int j = 0; j < 4; ++j) {
        ll row = bm + wr * 64 + m * 16 + cr + j;
        int col = bn + wc * 64 + n * 16 + cc;
        if constexpr (CBF)
          ((ushort*)C)[row * ldc + col] = f2b(acc[m][n][j]);
        else
          ((float*)C)[row * ldc + col] = acc[m][n][j];
      }
    }
  }
}

// ---------------- fp32-compute GEMM (kept for small batched CB) ------------
template <int ABF, int BBF, int CBF>
__global__ __launch_bounds__(256) void gemm_nt(
    const void* __restrict__ Av, const void* __restrict__ Bv, void* __restrict__ Cv,
    int M, int N, int K, int lda, int ldb, int ldc,
    ll batchA, ll batchB, ll batchC)
{
  __shared__ float As[16][128];
  __shared__ float Bs[16][128];
  const int t = threadIdx.x;
  const int bm = blockIdx.y * 128;
  const int bn = blockIdx.x * 128;
  const int tx = t & 15, ty = t >> 4;
  const int srow = t >> 1;
  const int sk = (t & 1) << 3;
  float acc[8][8] = {};

  const ll arow = (ll)blockIdx.z * batchA + (ll)(bm + srow) * lda;
  int brow_i = bn + srow; if (brow_i > N - 1) brow_i = N - 1;
  const ll brow = (ll)blockIdx.z * batchB + (ll)brow_i * ldb;
  const ll zc = (ll)blockIdx.z * batchC;

  for (int k0 = 0; k0 < K; k0 += 16) {
    __syncthreads();
    float av[8], bv[8];
    if constexpr (ABF) {
      uint4 ua = *(const uint4*)((const ushort*)Av + arow + k0 + sk);
      unpack8(ua, av);
    } else {
      const float* p = (const float*)Av + arow + k0 + sk;
      float4 x0 = *(const float4*)p, x1 = *(const float4*)(p + 4);
      av[0] = x0.x; av[1] = x0.y; av[2] = x0.z; av[3] = x0.w;
      av[4] = x1.x; av[5] = x1.y; av[6] = x1.z; av[7] = x1.w;
    }
    if constexpr (BBF) {
      uint4 ub = *(const uint4*)((const ushort*)Bv + brow + k0 + sk);
      unpack8(ub, bv);
    } else {
      const float* p = (const float*)Bv + brow + k0 + sk;
      float4 x0 = *(const float4*)p, x1 = *(const float4*)(p + 4);
      bv[0] = x0.x; bv[1] = x0.y; bv[2] = x0.z; bv[3] = x0.w;
      bv[4] = x1.x; bv[5] = x1.y; bv[6] = x1.z; bv[7] = x1.w;
    }
#pragma unroll
    for (int j = 0; j < 8; ++j) { As[sk + j][srow] = av[j]; Bs[sk + j][srow] = bv[j]; }
    __syncthreads();
#pragma unroll
    for (int k = 0; k < 16; ++k) {
      float a[8], b[8];
      *(float4*)&a[0] = *(const float4*)&As[k][ty * 4];
      *(float4*)&a[4] = *(const float4*)&As[k][64 + ty * 4];
      *(float4*)&b[0] = *(const float4*)&Bs[k][tx * 4];
      *(float4*)&b[4] = *(const float4*)&Bs[k][64 + tx * 4];
#pragma unroll
      for (int i = 0; i < 8; ++i)
#pragma unroll
        for (int j = 0; j < 8; ++j)
          acc[i][j] = fmaf(a[i], b[j], acc[i][j]);
    }
  }
#pragma unroll
  for (int i = 0; i < 8; ++i) {
    int r = bm + (i < 4 ? ty * 4 + i : 64 + ty * 4 + (i - 4));
    ll rb = zc + (ll)r * ldc;
    int c0 = bn + tx * 4;
    int c1 = bn + 64 + tx * 4;
    if constexpr (CBF) {
      if (c0 < N) {
        ushort4 s; s.x = f2b(acc[i][0]); s.y = f2b(acc[i][1]);
        s.z = f2b(acc[i][2]); s.w = f2b(acc[i][3]);
        *(ushort4*)((ushort*)Cv + rb + c0) = s;
      }
      if (c1 < N) {
        ushort4 s; s.x = f2b(acc[i][4]); s.y = f2b(acc[i][5]);
        s.z = f2b(acc[i][6]); s.w = f2b(acc[i][7]);
        *(ushort4*)((ushort*)Cv + rb + c1) = s;
      }
    } else {
      if (c0 < N)
        *(float4*)((float*)Cv + rb + c0) =
            make_float4(acc[i][0], acc[i][1], acc[i][2], acc[i][3]);
      if (c1 < N)
        *(float4*)((float*)Cv + rb + c1) =
            make_float4(acc[i][4], acc[i][5], acc[i][6], acc[i][7]);
    }
  }
}

// ---------------- depthwise conv (width 4, causal) + bias + SiLU -----------
__global__ __launch_bounds__(256) void conv_silu(
    const ushort* __restrict__ zx, const float* __restrict__ cw,
    const float* __restrict__ cbias, ushort* __restrict__ out)
{
  ll tid = (ll)blockIdx.x * 256 + threadIdx.x;  // one per (b,l,ch4); total 2*4096*1088
  int ch4 = (int)(tid % 1088) << 2;
  ll bl = tid / 1088;
  int l = (int)(bl & 4095);
  ll rowbase = bl - l;  // b*4096
  float4 acc = *(const float4*)&cbias[ch4];
  float4 w0 = *(const float4*)&cw[(ch4 + 0) * 4];
  float4 w1 = *(const float4*)&cw[(ch4 + 1) * 4];
  float4 w2 = *(const float4*)&cw[(ch4 + 2) * 4];
  float4 w3 = *(const float4*)&cw[(ch4 + 3) * 4];
#define TAP(W, COMP)                                                               \
  { int llx = l + (W) - 3;                                                         \
    if (llx >= 0) {                                                                \
      ushort4 xv = *(const ushort4*)&zx[(rowbase + llx) * 8576 + 4096 + ch4];      \
      acc.x = fmaf(b2f(xv.x), w0.COMP, acc.x);                                     \
      acc.y = fmaf(b2f(xv.y), w1.COMP, acc.y);                                     \
      acc.z = fmaf(b2f(xv.z), w2.COMP, acc.z);                                     \
      acc.w = fmaf(b2f(xv.w), w3.COMP, acc.w); } }
  TAP(0, x) TAP(1, y) TAP(2, z) TAP(3, w)
#undef TAP
  ushort4 o;
  o.x = f2b(silu_f(acc.x)); o.y = f2b(silu_f(acc.y));
  o.z = f2b(silu_f(acc.z)); o.w = f2b(silu_f(acc.w));
  *(ushort4*)&out[bl * 4352 + ch4] = o;
}

// ---------------- dt softplus + per-chunk cumsum of dt*A -------------------
__global__ __launch_bounds__(256) void dt_cumsum(
    const ushort* __restrict__ zx, const float* __restrict__ dt_bias,
    const float* __restrict__ A_log, float* __restrict__ dt_sp,
    float* __restrict__ dA)
{
  __shared__ float sdt[256][64];  // 64 KiB
  const int bc = blockIdx.x;
  const int t = threadIdx.x;
#pragma unroll
  for (int q = 0; q < 16; ++q) {
    int ff = q * 256 + t;
    int i = ff >> 4;
    int h4 = (ff & 15) << 2;
    ushort4 v4 = *(const ushort4*)&zx[((ll)bc * 256 + i) * 8576 + 8448 + h4];
    float4 bb = *(const float4*)&dt_bias[h4];
    float4 v;
    v.x = softplus_f(b2f(v4.x) + bb.x); v.y = softplus_f(b2f(v4.y) + bb.y);
    v.z = softplus_f(b2f(v4.z) + bb.z); v.w = softplus_f(b2f(v4.w) + bb.w);
    *(float4*)&dt_sp[((ll)bc * 256 + i) * 64 + h4] = v;
    *(float4*)&sdt[i][h4] = v;
  }
  __syncthreads();
  if (t < 64) {
    const int h = t;
    const float Ah = -expf(A_log[h]);
    float run = 0.0f;
    for (int i = 0; i < 256; ++i) {
      run = fmaf(sdt[i][h], Ah, run);
      dA[((ll)bc * 256 + i) * 64 + h] = run;
    }
  }
}

// ---------------- per-chunk end states: st[bc][h][p][n] (bf16) -------------
__global__ __launch_bounds__(256) void states_kernel(
    const ushort* __restrict__ xbc, const float* __restrict__ dt_sp,
    const float* __restrict__ dA, ushort* __restrict__ st)
{
  const int bc = blockIdx.x, h = blockIdx.y;
  const int t = threadIdx.x;
  __shared__ float sA[256], sdt[256];
  __shared__ float sxw[64][68];
  __shared__ float sB[64][132];
  sA[t]  = dA[((ll)bc * 256 + t) * 64 + h];
  sdt[t] = dt_sp[((ll)bc * 256 + t) * 64 + h];
  __syncthreads();
  const float dAlast = sA[255];
  const int pt = t & 15, nt = t >> 4;
  float acc[4][8] = {};

  for (int s0 = 0; s0 < 256; s0 += 64) {
    __syncthreads();
#pragma unroll
    for (int q = 0; q < 4; ++q) {   // stage x * (decay_last * dt): 64x64
      int ff = q * 256 + t;
      int s = ff >> 4, p4 = (ff & 15) << 2;
      float w = expf(dAlast - sA[s0 + s]) * sdt[s0 + s];
      ushort4 xv = *(const ushort4*)&xbc[((ll)bc * 256 + s0 + s) * 4352 + h * 64 + p4];
      float4 f;
      f.x = b2f(xv.x) * w; f.y = b2f(xv.y) * w;
      f.z = b2f(xv.z) * w; f.w = b2f(xv.w) * w;
      *(float4*)&sxw[s][p4] = f;
    }
#pragma unroll
    for (int q = 0; q < 8; ++q) {   // stage B: 64x128
      int ff = q * 256 + t;
      int s = ff >> 5, n4 = (ff & 31) << 2;
      ushort4 bv = *(const ushort4*)&xbc[((ll)bc * 256 + s0 + s) * 4352 + 4096 + n4];
      float4 f;
      f.x = b2f(bv.x); f.y = b2f(bv.y); f.z = b2f(bv.z); f.w = b2f(bv.w);
      *(float4*)&sB[s][n4] = f;
    }
    __syncthreads();
#pragma unroll 8
    for (int s = 0; s < 64; ++s) {
      float4 xv = *(const float4*)&sxw[s][pt * 4];
      float4 b0 = *(const float4*)&sB[s][nt * 8];
      float4 b1 = *(const float4*)&sB[s][nt * 8 + 4];
      float xa[4] = {xv.x, xv.y, xv.z, xv.w};
      float bb[8] = {b0.x, b0.y, b0.z, b0.w, b1.x, b1.y, b1.z, b1.w};
#pragma unroll
      for (int i = 0; i < 4; ++i)
#pragma unroll
        for (int j = 0; j < 8; ++j)
          acc[i][j] = fmaf(xa[i], bb[j], acc[i][j]);
    }
  }
  ll base = ((ll)bc * 64 + h) * 8192;
#pragma unroll
  for (int i = 0; i < 4; ++i) {
    int p = pt * 4 + i;
    ushort4 o0; o0.x = f2b(acc[i][0]); o0.y = f2b(acc[i][1]);
    o0.z = f2b(acc[i][2]); o0.w = f2b(acc[i][3]);
    ushort4 o1; o1.x = f2b(acc[i][4]); o1.y = f2b(acc[i][5]);
    o1.z = f2b(acc[i][6]); o1.w = f2b(acc[i][7]);
    *(ushort4*)&st[base + p * 128 + nt * 8] = o0;
    *(ushort4*)&st[base + p * 128 + nt * 8 + 4] = o1;
  }
}

// ---------------- inter-chunk scan, in place: st[c] := carry-before-chunk-c
__global__ __launch_bounds__(256) void scan_kernel(
    ushort* __restrict__ st, const float* __restrict__ dA)
{
  ll tid = (ll)blockIdx.x * 256 + threadIdx.x;  // 2*64*64*128 = 1,048,576
  int n = (int)(tid & 127);
  int p = (int)((tid >> 7) & 63);
  int h = (int)((tid >> 13) & 63);
  int b = (int)(tid >> 19);
  float s = 0.0f;  // carry stays fp32 in-register
#pragma unroll
  for (int c = 0; c < 16; ++c) {
    int bc = b * 16 + c;
    float dec = expf(dA[((ll)bc * 256 + 255) * 64 + h]);
    ll idx = ((ll)bc * 64 + h) * 8192 + p * 128 + n;
    float tmp = b2f(st[idx]);
    st[idx] = f2b(s);        // prev (state before this chunk)
    s = fmaf(s, dec, tmp);   // carry
  }
}

// ---------------- y = y_diag + y_off + Dp*x -> zx cols [4096,8192) (bf16) --
__global__ __launch_bounds__(256) void ssm_y(
    const ushort* __restrict__ xbc, const float* __restrict__ dt_sp,
    const float* __restrict__ dA, const ushort* __restrict__ CB,
    const ushort* __restrict__ prev, const float* __restrict__ Dp,
    ushort* __restrict__ zx)
{
  const int bc = blockIdx.x, h = blockIdx.y;
  const int t = threadIdx.x;
  const int pt = t & 3, it = t >> 2;  // rows i = it*4+{0..3}; cols p = pt*16+{0..15}
  const int p0 = pt * 16;
  __shared__ float sm[13120];
  float* sA  = sm;         // 256
  float* sdt = sm + 256;   // 256
  float* R   = sm + 512;
  float* sx  = R;          // phase1: [32][68]  = 2176
  float* sCB = R + 2176;   // phase1: [256][33] = 8448
  float* spv = R;          // phase2: [64][129] = 8256
  float* sCt = R + 8256;   // phase2: [256][17] = 4352

  sA[t]  = dA[((ll)bc * 256 + t) * 64 + h];
  sdt[t] = dt_sp[((ll)bc * 256 + t) * 64 + h];
  __syncthreads();
  float sAi[4], ei[4];
#pragma unroll
  for (int i = 0; i < 4; ++i) {
    sAi[i] = sA[it * 4 + i];
    ei[i] = expf(sAi[i]);
  }
  float acc[4][16] = {};

  // ---- phase 1: y_diag (masked M @ x) ----
  for (int jt = 0; jt < 8; ++jt) {
    __syncthreads();
#pragma unroll
    for (int q = 0; q < 2; ++q) {          // stage x j-tile 32x64
      int ff = q * 256 + t;
      int jj = ff >> 4, p4 = (ff & 15) << 2;
      ushort4 xv = *(const ushort4*)&xbc[((ll)bc * 256 + jt * 32 + jj) * 4352 + h * 64 + p4];
      float4 f;
      f.x = b2f(xv.x); f.y = b2f(xv.y); f.z = b2f(xv.z); f.w = b2f(xv.w);
      *(float4*)&sx[jj * 68 + p4] = f;
    }
#pragma unroll
    for (int q = 0; q < 8; ++q) {          // stage CB 256 x 32
      int ff = q * 256 + t;
      int i = ff >> 3, j4 = (ff & 7) << 2;
      ushort4 cv = *(const ushort4*)&CB[((ll)bc * 256 + i) * 256 + jt * 32 + j4];
      sCB[i * 33 + j4 + 0] = b2f(cv.x); sCB[i * 33 + j4 + 1] = b2f(cv.y);
      sCB[i * 33 + j4 + 2] = b2f(cv.z); sCB[i * 33 + j4 + 3] = b2f(cv.w);
    }
    __syncthreads();
    if (jt * 32 <= it * 4 + 3) {           // whole-tile triangular skip
      for (int jj = 0; jj < 32; ++jj) {
        int j = jt * 32 + jj;
        float dAj = sA[j];
        float dtj = sdt[j];
        float m[4];
#pragma unroll
        for (int i = 0; i < 4; ++i) {
          int irow = it * 4 + i;
          m[i] = (j <= irow) ? sCB[irow * 33 + jj] * expf(sAi[i] - dAj) * dtj : 0.0f;
        }
        float xv[16];
#pragma unroll
        for (int qq = 0; qq < 4; ++qq)
          *(float4*)&xv[qq * 4] = *(const float4*)&sx[jj * 68 + p0 + qq * 4];
#pragma unroll
        for (int i = 0; i < 4; ++i)
#pragma unroll
          for (int q = 0; q < 16; ++q)
            acc[i][q] = fmaf(m[i], xv[q], acc[i][q]);
      }
    }
  }

  // ---- phase 2: y_off = exp(dA_i) * C @ prev^T ----
  __syncthreads();
#pragma unroll
  for (int q = 0; q < 8; ++q) {            // stage prev[p][n] 64x128
    int ff = q * 256 + t;
    int p = ff >> 5, n4 = (ff & 31) << 2;
    ushort4 pv = *(const ushort4*)&prev[((ll)bc * 64 + h) * 8192 + p * 128 + n4];
    spv[p * 129 + n4 + 0] = b2f(pv.x); spv[p * 129 + n4 + 1] = b2f(pv.y);
    spv[p * 129 + n4 + 2] = b2f(pv.z); spv[p * 129 + n4 + 3] = b2f(pv.w);
  }
  for (int n0 = 0; n0 < 128; n0 += 16) {
    __syncthreads();
#pragma unroll
    for (int q = 0; q < 4; ++q) {          // stage C n-tile 256x16
      int ff = q * 256 + t;
      int i = ff >> 2, n4 = (ff & 3) << 2;
      ushort4 cv = *(const ushort4*)&xbc[((ll)bc * 256 + i) * 4352 + 4224 + n0 + n4];
      sCt[i * 17 + n4 + 0] = b2f(cv.x); sCt[i * 17 + n4 + 1] = b2f(cv.y);
      sCt[i * 17 + n4 + 2] = b2f(cv.z); sCt[i * 17 + n4 + 3] = b2f(cv.w);
    }
    __syncthreads();
    for (int nn = 0; nn < 16; ++nn) {
      int n = n0 + nn;
      float cc[4];
#pragma unroll
      for (int i = 0; i < 4; ++i)
        cc[i] = sCt[(it * 4 + i) * 17 + nn] * ei[i];
      float pv[16];
#pragma unroll
      for (int q = 0; q < 16; ++q)
        pv[q] = spv[(p0 + q) * 129 + n];
#pragma unroll
      for (int i = 0; i < 4; ++i)
#pragma unroll
        for (int q = 0; q < 16; ++q)
          acc[i][q] = fmaf(cc[i], pv[q], acc[i][q]);
    }
  }

  // ---- epilogue: + Dp*x, store bf16 into zx cols [4096+h*64+p] ----
  float dph = Dp[h];
#pragma unroll
  for (int i = 0; i < 4; ++i) {
    ll row = (ll)bc * 256 + it * 4 + i;
#pragma unroll
    for (int qq = 0; qq < 4; ++qq) {
      ushort4 xv = *(const ushort4*)&xbc[row * 4352 + h * 64 + p0 + qq * 4];
      ushort4 o;
      o.x = f2b(acc[i][qq * 4 + 0] + dph * b2f(xv.x));
      o.y = f2b(acc[i][qq * 4 + 1] + dph * b2f(xv.y));
      o.z = f2b(acc[i][qq * 4 + 2] + dph * b2f(xv.z));
      o.w = f2b(acc[i][qq * 4 + 3] + dph * b2f(xv.w));
      *(ushort4*)&zx[row * 8576 + 4096 + h * 64 + p0 + qq * 4] = o;
    }
  }
}

// ---------------- gated RMSNorm, in place on zx cols [4096,8192) -----------
__global__ __launch_bounds__(256) void gated_rmsnorm(
    ushort* __restrict__ zx, const float* __restrict__ norm_w)
{
  const ll row = blockIdx.x;
  ushort* zrow = zx + row * 8576;
  ushort* yrow = zrow + 4096;
  const int t = threadIdx.x;
  float g[16];
  float ss = 0.0f;
#pragma unroll
  for (int q = 0; q < 2; ++q) {
    int d = q * 2048 + t * 8;
    uint4 yv = *(const uint4*)&yrow[d];
    uint4 zv = *(const uint4*)&zrow[d];
    float yf[8], zf[8];
    unpack8(yv, yf);
    unpack8(zv, zf);
#pragma unroll
    for (int j = 0; j < 8; ++j) {
      float gv = yf[j] * silu_f(zf[j]);
      g[q * 8 + j] = gv;
      ss += gv * gv;
    }
  }
#pragma unroll
  for (int o = 32; o > 0; o >>= 1) ss += __shfl_xor(ss, o);
  __shared__ float red[4];
  if ((t & 63) == 0) red[t >> 6] = ss;
  __syncthreads();
  ss = red[0] + red[1] + red[2] + red[3];
  float scale = rsqrtf(ss * (1.0f / 4096.0f) + 1e-5f);
#pragma unroll
  for (int q = 0; q < 2; ++q) {
    int d = q * 2048 + t * 8;
    float4 w0 = *(const float4*)&norm_w[d];
    float4 w1 = *(const float4*)&norm_w[d + 4];
    uint4 o;
    o.x = pk2(g[q * 8 + 0] * scale * w0.x, g[q * 8 + 1] * scale * w0.y);
    o.y = pk2(g[q * 8 + 2] * scale * w0.z, g[q * 8 + 3] * scale * w0.w);
    o.z = pk2(g[q * 8 + 4] * scale * w1.x, g[q * 8 + 5] * scale * w1.y);
    o.w = pk2(g[q * 8 + 6] * scale * w1.z, g[q * 8 + 7] * scale * w1.w);
    *(uint4*)&yrow[d] = o;
  }
}

extern "C" void kernel_launch(void* const* d_in, const int* in_sizes, int n_in,
                              void* d_out, int out_size, void* d_ws, size_t ws_size,
                              hipStream_t stream) {
  const float* u       = (const float*)d_in[0];
  const float* W_in    = (const float*)d_in[1];
  const float* conv_w  = (const float*)d_in[2];
  const float* conv_b  = (const float*)d_in[3];
  const float* dt_bias = (const float*)d_in[4];
  const float* A_log   = (const float*)d_in[5];
  const float* Dp      = (const float*)d_in[6];
  const float* norm_w  = (const float*)d_in[7];
  const float* W_out   = (const float*)d_in[8];
  float* out = (float*)d_out;

  char* wsb = (char*)d_ws;
  ushort* zx      = (ushort*)wsb;                    // [8192][8576] bf16
  ushort* xbc     = (ushort*)(wsb + 140509184LL);    // [8192][4352] bf16
  ushort* u_bf    = xbc;                             // alias (dead after gemm1)
  ushort* Win_bf  = (ushort*)(wsb + 174063616LL);    // alias inside xbc region
  ushort* st      = (ushort*)(wsb + 211812352LL);    // [32][64][64][128] bf16
  ushort* Wout_bf = st;                              // alias (st dead after ssm_y)
  ushort* CBb     = (ushort*)(wsb + 245366784LL);
  float*  dt_sp   = (float*)(wsb + 249561088LL);
  float*  dAcs    = (float*)(wsb + 251658240LL);
  // total 253,755,392 B = 242 MiB

  // 0. fp32 -> bf16 operand conversion
  f32_to_bf16<<<8192, 256, 0, stream>>>(u, u_bf, 16777216LL);
  f32_to_bf16<<<8512, 256, 0, stream>>>(W_in, Win_bf, 17432576LL);
  // 1. in_proj: zx = u @ W_in^T   [8192 x 8512(pad 8576), K=2048]  MFMA
  gemm_mfma<1><<<dim3(67, 64), 256, 0, stream>>>(
      u_bf, Win_bf, zx, 8512, 2048, 2048, 2048, 8576);
  // 2. causal conv + SiLU
  conv_silu<<<34816, 256, 0, stream>>>(zx, conv_w, conv_b, xbc);
  // 3. dt softplus + chunk cumsum
  dt_cumsum<<<32, 256, 0, stream>>>(zx, dt_bias, A_log, dt_sp, dAcs);
  // 4. CB[bc][i][j] = C_i . B_j  (batched 256x256, K=128)
  gemm_nt<1, 1, 1><<<dim3(2, 2, 32), 256, 0, stream>>>(
      xbc + 4224, xbc + 4096, CBb, 256, 256, 128,
      4352, 4352, 256, 256LL * 4352, 256LL * 4352, 65536LL);
  // 5. per-chunk end states
  states_kernel<<<dim3(32, 64), 256, 0, stream>>>(xbc, dt_sp, dAcs, st);
  // 6. inter-chunk scan (in place: st becomes prev)
  scan_kernel<<<4096, 256, 0, stream>>>(st, dAcs);
  // 7. y_diag + y_off + Dp*x  -> zx cols [4096,8192)
  ssm_y<<<dim3(32, 64), 256, 0, stream>>>(xbc, dt_sp, dAcs, CBb, st, Dp, zx);
  // 8. gated RMSNorm (in place)
  gated_rmsnorm<<<8192, 256, 0, stream>>>(zx, norm_w);
  // 9. W_out -> bf16 (into dead st region), then out_proj MFMA
  f32_to_bf16<<<4096, 256, 0, stream>>>(W_out, Wout_bf, 8388608LL);
  gemm_mfma<0><<<dim3(16, 64), 256, 0, stream>>>(
      zx + 4096, Wout_bf, out, 2048, 4096, 8576, 4096, 2048);
}

// Round 11
// 1109.671 us; speedup vs baseline: 5.2975x; 1.6161x over previous
//
#include <hip/hip_runtime.h>
#include <hip/hip_bf16.h>

typedef long long ll;
typedef unsigned int uint;
typedef unsigned short ushort;

typedef __bf16 bf16x8 __attribute__((ext_vector_type(8)));
typedef float f32x4 __attribute__((ext_vector_type(4)));

// Problem constants
// B=2, L=4096, D_MODEL=2048, D_INNER=4096, D_STATE=128, N_HEADS=64, D_HEAD=64
// CONV_DIM=4352, D_IN_PROJ=8512 (padded to 8576 = 67*128), CHUNK=256, 32 chunks
//
// Workspace (244 MiB):
//   zx    bf16 [8192][8576]      @ 0            (z | xBC_raw->y | dt_raw | pad)
//   xbc   bf16 [8192][4352]      @ 140,509,184  (aliased early: u_bf, Win_bf)
//   st    bf16 [32][64][64][128] @ 211,812,352  (aliased late: Wout_bf)
//   CB    bf16 [32][256][256]    @ 245,366,784
//   dt_sp f32  [8192][64]        @ 249,561,088
//   dAcs  f32  [8192][64]        @ 251,658,240
//   BT    bf16 [32][128][256]    @ 253,755,392   (end 255,852,544)

__device__ __forceinline__ float silu_f(float x) { return x / (1.0f + expf(-x)); }
__device__ __forceinline__ float softplus_f(float x) {
  return x > 20.0f ? x : log1pf(expf(x));
}
__device__ __forceinline__ float b2f(ushort u) {
  return __uint_as_float(((uint)u) << 16);
}
__device__ __forceinline__ ushort f2b(float f) {
  uint x = __float_as_uint(f);
  return (ushort)((x + 0x7FFFu + ((x >> 16) & 1u)) >> 16);
}
__device__ __forceinline__ uint pk2(float a, float b) {
  return (uint)f2b(a) | ((uint)f2b(b) << 16);
}
__device__ __forceinline__ void unpack8(uint4 u, float* f) {
  f[0] = b2f((ushort)(u.x & 0xffff)); f[1] = b2f((ushort)(u.x >> 16));
  f[2] = b2f((ushort)(u.y & 0xffff)); f[3] = b2f((ushort)(u.y >> 16));
  f[4] = b2f((ushort)(u.z & 0xffff)); f[5] = b2f((ushort)(u.z >> 16));
  f[6] = b2f((ushort)(u.w & 0xffff)); f[7] = b2f((ushort)(u.w >> 16));
}
__device__ __forceinline__ void unpack8u(uint4 u, ushort* e) {
  e[0] = (ushort)(u.x & 0xffff); e[1] = (ushort)(u.x >> 16);
  e[2] = (ushort)(u.y & 0xffff); e[3] = (ushort)(u.y >> 16);
  e[4] = (ushort)(u.z & 0xffff); e[5] = (ushort)(u.z >> 16);
  e[6] = (ushort)(u.w & 0xffff); e[7] = (ushort)(u.w >> 16);
}

#define GLDS16(g, l)                                                     \
  __builtin_amdgcn_global_load_lds(                                      \
      (const __attribute__((address_space(1))) void*)(g),                \
      (__attribute__((address_space(3))) void*)(l), 16, 0, 0)

// ---------------- f32 -> bf16 convert (8 elems/thread) ---------------------
__global__ __launch_bounds__(256) void f32_to_bf16(
    const float* __restrict__ in, ushort* __restrict__ out, ll n)
{
  ll i = ((ll)blockIdx.x * 256 + threadIdx.x) * 8;
  if (i + 8 > n) return;
  float4 a = *(const float4*)&in[i];
  float4 b = *(const float4*)&in[i + 4];
  ushort4 o0; o0.x = f2b(a.x); o0.y = f2b(a.y); o0.z = f2b(a.z); o0.w = f2b(a.w);
  ushort4 o1; o1.x = f2b(b.x); o1.y = f2b(b.y); o1.z = f2b(b.z); o1.w = f2b(b.w);
  *(ushort4*)&out[i] = o0;
  *(ushort4*)&out[i + 4] = o1;
}

// ---------------- bf16 MFMA GEMM: C[M,N] = A[M,K] @ B[N,K]^T ---------------
// m97 structure: 128x128 tile, BK=32, 256 thr = 4 waves (2x2), 64x64/wave.
// M%128==0, K%32==0, grid.x*128 cols allocated in C (Nreal only load-clamped).
template <int CBF>  // 1: bf16 C, 0: f32 C
__global__ __launch_bounds__(256) void gemm_mfma(
    const ushort* __restrict__ A, const ushort* __restrict__ B, void* __restrict__ C,
    int Nreal, int K, int lda, int ldb, int ldc,
    ll batchA, ll batchB, ll batchC)
{
  A += (ll)blockIdx.z * batchA;
  B += (ll)blockIdx.z * batchB;
  __shared__ ushort As[128 * 32];
  __shared__ ushort Bs[128 * 32];
  const int t = threadIdx.x;
  const int lane = t & 63, w = t >> 6;
  const int wr = w >> 1, wc = w & 1;
  const int bm = blockIdx.y * 128, bn = blockIdx.x * 128;

  const int srow = t >> 2, skc = (t & 3) << 3;
  const ll a0 = (ll)(bm + srow) * lda + skc;
  const ll a1 = (ll)(bm + 64 + srow) * lda + skc;
  int br0 = bn + srow;      if (br0 >= Nreal) br0 = Nreal - 1;
  int br1 = bn + 64 + srow; if (br1 >= Nreal) br1 = Nreal - 1;
  const ll b0 = (ll)br0 * ldb + skc;
  const ll b1 = (ll)br1 * ldb + skc;
  ushort* lA0 = As + t * 8;        ushort* lA1 = As + 2048 + t * 8;
  ushort* lB0 = Bs + t * 8;        ushort* lB1 = Bs + 2048 + t * 8;

  f32x4 acc[4][4];
#pragma unroll
  for (int m = 0; m < 4; ++m)
#pragma unroll
    for (int n = 0; n < 4; ++n) acc[m][n] = (f32x4){0.f, 0.f, 0.f, 0.f};

  const int fr = lane & 15;
  const int fk = (lane >> 4) << 3;

  for (int k0 = 0; k0 < K; k0 += 32) {
    GLDS16(A + a0 + k0, lA0);
    GLDS16(A + a1 + k0, lA1);
    GLDS16(B + b0 + k0, lB0);
    GLDS16(B + b1 + k0, lB1);
    __syncthreads();
    bf16x8 af[4], bf[4];
#pragma unroll
    for (int m = 0; m < 4; ++m)
      af[m] = *(const bf16x8*)&As[(wr * 64 + m * 16 + fr) * 32 + fk];
#pragma unroll
    for (int n = 0; n < 4; ++n)
      bf[n] = *(const bf16x8*)&Bs[(wc * 64 + n * 16 + fr) * 32 + fk];
#pragma unroll
    for (int m = 0; m < 4; ++m)
#pragma unroll
      for (int n = 0; n < 4; ++n)
        acc[m][n] = __builtin_amdgcn_mfma_f32_16x16x32_bf16(af[m], bf[n], acc[m][n], 0, 0, 0);
    __syncthreads();
  }

  const int cr = (lane >> 4) << 2, cc = lane & 15;
  const ll zc = (ll)blockIdx.z * batchC;
#pragma unroll
  for (int m = 0; m < 4; ++m) {
#pragma unroll
    for (int n = 0; n < 4; ++n) {
#pragma unroll
      for (int j = 0; j < 4; ++j) {
        ll row = bm + wr * 64 + m * 16 + cr + j;
        int col = bn + wc * 64 + n * 16 + cc;
        if constexpr (CBF)
          ((ushort*)C)[zc + row * ldc + col] = f2b(acc[m][n][j]);
        else
          ((float*)C)[zc + row * ldc + col] = acc[m][n][j];
      }
    }
  }
}

// ---------------- depthwise conv (width 4, causal) + bias + SiLU -----------
__global__ __launch_bounds__(256) void conv_silu(
    const ushort* __restrict__ zx, const float* __restrict__ cw,
    const float* __restrict__ cbias, ushort* __restrict__ out)
{
  ll tid = (ll)blockIdx.x * 256 + threadIdx.x;
  int ch4 = (int)(tid % 1088) << 2;
  ll bl = tid / 1088;
  int l = (int)(bl & 4095);
  ll rowbase = bl - l;
  float4 acc = *(const float4*)&cbias[ch4];
  float4 w0 = *(const float4*)&cw[(ch4 + 0) * 4];
  float4 w1 = *(const float4*)&cw[(ch4 + 1) * 4];
  float4 w2 = *(const float4*)&cw[(ch4 + 2) * 4];
  float4 w3 = *(const float4*)&cw[(ch4 + 3) * 4];
#define TAP(W, COMP)                                                               \
  { int llx = l + (W) - 3;                                                         \
    if (llx >= 0) {                                                                \
      ushort4 xv = *(const ushort4*)&zx[(rowbase + llx) * 8576 + 4096 + ch4];      \
      acc.x = fmaf(b2f(xv.x), w0.COMP, acc.x);                                     \
      acc.y = fmaf(b2f(xv.y), w1.COMP, acc.y);                                     \
      acc.z = fmaf(b2f(xv.z), w2.COMP, acc.z);                                     \
      acc.w = fmaf(b2f(xv.w), w3.COMP, acc.w); } }
  TAP(0, x) TAP(1, y) TAP(2, z) TAP(3, w)
#undef TAP
  ushort4 o;
  o.x = f2b(silu_f(acc.x)); o.y = f2b(silu_f(acc.y));
  o.z = f2b(silu_f(acc.z)); o.w = f2b(silu_f(acc.w));
  *(ushort4*)&out[bl * 4352 + ch4] = o;
}

// ---------------- dt softplus + per-chunk cumsum of dt*A -------------------
__global__ __launch_bounds__(256) void dt_cumsum(
    const ushort* __restrict__ zx, const float* __restrict__ dt_bias,
    const float* __restrict__ A_log, float* __restrict__ dt_sp,
    float* __restrict__ dA)
{
  __shared__ float sdt[256][64];
  const int bc = blockIdx.x;
  const int t = threadIdx.x;
#pragma unroll
  for (int q = 0; q < 16; ++q) {
    int ff = q * 256 + t;
    int i = ff >> 4;
    int h4 = (ff & 15) << 2;
    ushort4 v4 = *(const ushort4*)&zx[((ll)bc * 256 + i) * 8576 + 8448 + h4];
    float4 bb = *(const float4*)&dt_bias[h4];
    float4 v;
    v.x = softplus_f(b2f(v4.x) + bb.x); v.y = softplus_f(b2f(v4.y) + bb.y);
    v.z = softplus_f(b2f(v4.z) + bb.z); v.w = softplus_f(b2f(v4.w) + bb.w);
    *(float4*)&dt_sp[((ll)bc * 256 + i) * 64 + h4] = v;
    *(float4*)&sdt[i][h4] = v;
  }
  __syncthreads();
  if (t < 64) {
    const int h = t;
    const float Ah = -expf(A_log[h]);
    float run = 0.0f;
    for (int i = 0; i < 256; ++i) {
      run = fmaf(sdt[i][h], Ah, run);
      dA[((ll)bc * 256 + i) * 64 + h] = run;
    }
  }
}

// ---------------- transpose B cols of xbc -> BT[bc][n][s] ------------------
__global__ __launch_bounds__(256) void bt_transpose(
    const ushort* __restrict__ xbc, ushort* __restrict__ BT)
{
  const int bc = blockIdx.x;
  const int st0 = blockIdx.y * 64;     // s tile
  const int nt0 = blockIdx.z * 64;     // n tile
  const int t = threadIdx.x;
  const int s_loc = t & 63, strip = t >> 6;
  const int nb = nt0 + strip * 16;
  const ll row = (ll)(bc * 256 + st0 + s_loc) * 4352 + 4096 + nb;
  uint4 v0 = *(const uint4*)&xbc[row];
  uint4 v1 = *(const uint4*)&xbc[row + 8];
  ushort e[16];
  unpack8u(v0, e); unpack8u(v1, e + 8);
#pragma unroll
  for (int k = 0; k < 16; ++k)
    BT[((ll)bc * 128 + nb + k) * 256 + st0 + s_loc] = e[k];
}

// ---------------- per-chunk end states via MFMA: st[bc][h][p][n] -----------
// A = (x .* w)^T [64 p][256 s] staged in LDS; B from BT[bc][n][s] (global).
__global__ __launch_bounds__(256) void states_mfma(
    const ushort* __restrict__ xbc, const float* __restrict__ dt_sp,
    const float* __restrict__ dA, const ushort* __restrict__ BT,
    ushort* __restrict__ st)
{
  const int bc = blockIdx.x, h = blockIdx.y;
  const int t = threadIdx.x, lane = t & 63, w = t >> 6;
  __shared__ ushort xwT[64][264];   // [p][s], pad to 264
  // stage: thread t handles s = t
  const float dAl = dA[((ll)bc * 256 + 255) * 64 + h];
  const float wloc = expf(dAl - dA[((ll)bc * 256 + t) * 64 + h]) *
                     dt_sp[((ll)bc * 256 + t) * 64 + h];
  {
    const ll xrow = ((ll)bc * 256 + t) * 4352 + h * 64;
#pragma unroll
    for (int g = 0; g < 8; ++g) {
      uint4 v = *(const uint4*)&xbc[xrow + g * 8];
      float f[8]; unpack8(v, f);
#pragma unroll
      for (int j = 0; j < 8; ++j)
        xwT[g * 8 + j][t] = f2b(f[j] * wloc);
    }
  }
  __syncthreads();

  const int fr = lane & 15, fk = (lane >> 4) << 3;
  f32x4 acc[4][2];
#pragma unroll
  for (int m = 0; m < 4; ++m)
#pragma unroll
    for (int n = 0; n < 2; ++n) acc[m][n] = (f32x4){0.f, 0.f, 0.f, 0.f};

  for (int s0 = 0; s0 < 256; s0 += 32) {
    bf16x8 af[4], bf[2];
#pragma unroll
    for (int m = 0; m < 4; ++m)
      af[m] = *(const bf16x8*)&xwT[m * 16 + fr][s0 + fk];
#pragma unroll
    for (int n = 0; n < 2; ++n)
      bf[n] = *(const bf16x8*)&BT[((ll)bc * 128 + w * 32 + n * 16 + fr) * 256 + s0 + fk];
#pragma unroll
    for (int m = 0; m < 4; ++m)
#pragma unroll
      for (int n = 0; n < 2; ++n)
        acc[m][n] = __builtin_amdgcn_mfma_f32_16x16x32_bf16(af[m], bf[n], acc[m][n], 0, 0, 0);
  }

  const int cr = (lane >> 4) << 2, cc = lane & 15;
  const ll base = ((ll)bc * 64 + h) * 8192;
#pragma unroll
  for (int m = 0; m < 4; ++m)
#pragma unroll
    for (int n = 0; n < 2; ++n)
#pragma unroll
      for (int j = 0; j < 4; ++j) {
        int p = m * 16 + cr + j;
        int nn = w * 32 + n * 16 + cc;
        st[base + p * 128 + nn] = f2b(acc[m][n][j]);
      }
}

// ---------------- inter-chunk scan, in place: st[c] := carry-before-chunk-c
__global__ __launch_bounds__(256) void scan_kernel(
    ushort* __restrict__ st, const float* __restrict__ dA)
{
  ll tid = (ll)blockIdx.x * 256 + threadIdx.x;
  int n = (int)(tid & 127);
  int p = (int)((tid >> 7) & 63);
  int h = (int)((tid >> 13) & 63);
  int b = (int)(tid >> 19);
  float s = 0.0f;
#pragma unroll
  for (int c = 0; c < 16; ++c) {
    int bc = b * 16 + c;
    float dec = expf(dA[((ll)bc * 256 + 255) * 64 + h]);
    ll idx = ((ll)bc * 64 + h) * 8192 + p * 128 + n;
    float tmp = b2f(st[idx]);
    st[idx] = f2b(s);
    s = fmaf(s, dec, tmp);
  }
}

// ---------------- y = y_diag + y_off + Dp*x via MFMA -> zx cols [4096,8192)
// Block (bc,h), 4 waves; wave w owns rows i in [w*64,(w+1)*64), all 64 p.
// K = 256 (masked M part, triangular-skipped) + 128 (C @ prev^T part).
__global__ __launch_bounds__(256) void ssm_y_mfma(
    const ushort* __restrict__ xbc, const float* __restrict__ dt_sp,
    const float* __restrict__ dA, const ushort* __restrict__ CB,
    const ushort* __restrict__ prev, const float* __restrict__ Dp,
    ushort* __restrict__ zx)
{
  const int bc = blockIdx.x, h = blockIdx.y;
  const int t = threadIdx.x, lane = t & 63, w = t >> 6;
  __shared__ float sA[256], sdt[256];
  __shared__ ushort xT[64][264];    // x^T [p][j]
  __shared__ ushort pv[64][136];    // prev [p][n]

  sA[t]  = dA[((ll)bc * 256 + t) * 64 + h];
  sdt[t] = dt_sp[((ll)bc * 256 + t) * 64 + h];
  {  // stage xT: thread t reads x row j=t (64 elems), writes column t
    const ll xrow = ((ll)bc * 256 + t) * 4352 + h * 64;
#pragma unroll
    for (int g = 0; g < 8; ++g) {
      uint4 v = *(const uint4*)&xbc[xrow + g * 8];
      ushort e[8]; unpack8u(v, e);
#pragma unroll
      for (int j = 0; j < 8; ++j) xT[g * 8 + j][t] = e[j];
    }
  }
  {  // stage prev: thread t -> p = t>>2, n block (t&3)*32
    const int p = t >> 2, n0 = (t & 3) * 32;
    const ll pb = ((ll)bc * 64 + h) * 8192 + (ll)p * 128 + n0;
#pragma unroll
    for (int g = 0; g < 4; ++g)
      *(uint4*)&pv[p][n0 + g * 8] = *(const uint4*)&prev[pb + g * 8];
  }
  __syncthreads();

  const int fr = lane & 15, fk = (lane >> 4) << 3;
  float dAi[4], ei[4];
  int im[4];
#pragma unroll
  for (int m = 0; m < 4; ++m) {
    im[m] = w * 64 + m * 16 + fr;
    dAi[m] = sA[im[m]];
    ei[m] = __expf(dAi[m]);
  }

  f32x4 acc[4][4];
#pragma unroll
  for (int m = 0; m < 4; ++m)
#pragma unroll
    for (int n = 0; n < 4; ++n) acc[m][n] = (f32x4){0.f, 0.f, 0.f, 0.f};

  // ---- masked M part: j-steps, triangular skip per wave ----
  const int nsteps = 2 * w + 2;
  for (int js = 0; js < nsteps; ++js) {
    const int j0 = js * 32;
    bf16x8 bf[4];
#pragma unroll
    for (int n = 0; n < 4; ++n)
      bf[n] = *(const bf16x8*)&xT[n * 16 + fr][j0 + fk];
    bf16x8 af[4];
#pragma unroll
    for (int m = 0; m < 4; ++m) {
      uint4 cb4 = *(const uint4*)&CB[((ll)bc * 256 + im[m]) * 256 + j0 + fk];
      float cb[8]; unpack8(cb4, cb);
#pragma unroll
      for (int jj = 0; jj < 8; ++jj) {
        int j = j0 + fk + jj;
        float mv = cb[jj] * sdt[j] * __expf(dAi[m] - sA[j]);
        af[m][jj] = (__bf16)((j <= im[m]) ? mv : 0.0f);
      }
    }
#pragma unroll
    for (int m = 0; m < 4; ++m)
#pragma unroll
      for (int n = 0; n < 4; ++n)
        acc[m][n] = __builtin_amdgcn_mfma_f32_16x16x32_bf16(af[m], bf[n], acc[m][n], 0, 0, 0);
  }

  // ---- y_off part: K over n (state dim), A = C*exp(dA_i), B = prev ----
  for (int ns = 0; ns < 4; ++ns) {
    const int n0 = ns * 32;
    bf16x8 bf[4];
#pragma unroll
    for (int n = 0; n < 4; ++n)
      bf[n] = *(const bf16x8*)&pv[n * 16 + fr][n0 + fk];
    bf16x8 af[4];
#pragma unroll
    for (int m = 0; m < 4; ++m) {
      uint4 cv4 = *(const uint4*)&xbc[((ll)bc * 256 + im[m]) * 4352 + 4224 + n0 + fk];
      float cv[8]; unpack8(cv4, cv);
#pragma unroll
      for (int jj = 0; jj < 8; ++jj)
        af[m][jj] = (__bf16)(cv[jj] * ei[m]);
    }
#pragma unroll
    for (int m = 0; m < 4; ++m)
#pragma unroll
      for (int n = 0; n < 4; ++n)
        acc[m][n] = __builtin_amdgcn_mfma_f32_16x16x32_bf16(af[m], bf[n], acc[m][n], 0, 0, 0);
  }

  // ---- epilogue: + Dp*x (x from xT tile), store bf16 ----
  const int cr = (lane >> 4) << 2, cc = lane & 15;
  const float dph = Dp[h];
#pragma unroll
  for (int m = 0; m < 4; ++m) {
#pragma unroll
    for (int n = 0; n < 4; ++n) {
#pragma unroll
      for (int j = 0; j < 4; ++j) {
        int i_loc = w * 64 + m * 16 + cr + j;
        int p = n * 16 + cc;
        float xval = b2f(xT[p][i_loc]);
        float val = acc[m][n][j] + dph * xval;
        zx[((ll)bc * 256 + i_loc) * 8576 + 4096 + h * 64 + p] = f2b(val);
      }
    }
  }
}

// ---------------- gated RMSNorm, in place on zx cols [4096,8192) -----------
__global__ __launch_bounds__(256) void gated_rmsnorm(
    ushort* __restrict__ zx, const float* __restrict__ norm_w)
{
  const ll row = blockIdx.x;
  ushort* zrow = zx + row * 8576;
  ushort* yrow = zrow + 4096;
  const int t = threadIdx.x;
  float g[16];
  float ss = 0.0f;
#pragma unroll
  for (int q = 0; q < 2; ++q) {
    int d = q * 2048 + t * 8;
    uint4 yv = *(const uint4*)&yrow[d];
    uint4 zv = *(const uint4*)&zrow[d];
    float yf[8], zf[8];
    unpack8(yv, yf);
    unpack8(zv, zf);
#pragma unroll
    for (int j = 0; j < 8; ++j) {
      float gv = yf[j] * silu_f(zf[j]);
      g[q * 8 + j] = gv;
      ss += gv * gv;
    }
  }
#pragma unroll
  for (int o = 32; o > 0; o >>= 1) ss += __shfl_xor(ss, o);
  __shared__ float red[4];
  if ((t & 63) == 0) red[t >> 6] = ss;
  __syncthreads();
  ss = red[0] + red[1] + red[2] + red[3];
  float scale = rsqrtf(ss * (1.0f / 4096.0f) + 1e-5f);
#pragma unroll
  for (int q = 0; q < 2; ++q) {
    int d = q * 2048 + t * 8;
    float4 w0 = *(const float4*)&norm_w[d];
    float4 w1 = *(const float4*)&norm_w[d + 4];
    uint4 o;
    o.x = pk2(g[q * 8 + 0] * scale * w0.x, g[q * 8 + 1] * scale * w0.y);
    o.y = pk2(g[q * 8 + 2] * scale * w0.z, g[q * 8 + 3] * scale * w0.w);
    o.z = pk2(g[q * 8 + 4] * scale * w1.x, g[q * 8 + 5] * scale * w1.y);
    o.w = pk2(g[q * 8 + 6] * scale * w1.z, g[q * 8 + 7] * scale * w1.w);
    *(uint4*)&yrow[d] = o;
  }
}

extern "C" void kernel_launch(void* const* d_in, const int* in_sizes, int n_in,
                              void* d_out, int out_size, void* d_ws, size_t ws_size,
                              hipStream_t stream) {
  const float* u       = (const float*)d_in[0];
  const float* W_in    = (const float*)d_in[1];
  const float* conv_w  = (const float*)d_in[2];
  const float* conv_b  = (const float*)d_in[3];
  const float* dt_bias = (const float*)d_in[4];
  const float* A_log   = (const float*)d_in[5];
  const float* Dp      = (const float*)d_in[6];
  const float* norm_w  = (const float*)d_in[7];
  const float* W_out   = (const float*)d_in[8];
  float* out = (float*)d_out;

  char* wsb = (char*)d_ws;
  ushort* zx      = (ushort*)wsb;                    // [8192][8576] bf16
  ushort* xbc     = (ushort*)(wsb + 140509184LL);    // [8192][4352] bf16
  ushort* u_bf    = xbc;                             // alias (dead after gemm1)
  ushort* Win_bf  = (ushort*)(wsb + 174063616LL);    // alias inside xbc region
  ushort* st      = (ushort*)(wsb + 211812352LL);    // [32][64][64][128] bf16
  ushort* Wout_bf = st;                              // alias (st dead after ssm_y)
  ushort* CBb     = (ushort*)(wsb + 245366784LL);
  float*  dt_sp   = (float*)(wsb + 249561088LL);
  float*  dAcs    = (float*)(wsb + 251658240LL);
  ushort* BT      = (ushort*)(wsb + 253755392LL);    // [32][128][256] bf16
  // total 255,852,544 B = 244 MiB

  // 0. fp32 -> bf16 operand conversion
  f32_to_bf16<<<8192, 256, 0, stream>>>(u, u_bf, 16777216LL);
  f32_to_bf16<<<8512, 256, 0, stream>>>(W_in, Win_bf, 17432576LL);
  // 1. in_proj: zx = u @ W_in^T   [8192 x 8512(pad 8576), K=2048]  MFMA
  gemm_mfma<1><<<dim3(67, 64), 256, 0, stream>>>(
      u_bf, Win_bf, zx, 8512, 2048, 2048, 2048, 8576, 0, 0, 0);
  // 2. causal conv + SiLU
  conv_silu<<<34816, 256, 0, stream>>>(zx, conv_w, conv_b, xbc);
  // 3. dt softplus + chunk cumsum
  dt_cumsum<<<32, 256, 0, stream>>>(zx, dt_bias, A_log, dt_sp, dAcs);
  // 4. B^T per chunk for states
  bt_transpose<<<dim3(32, 4, 2), 256, 0, stream>>>(xbc, BT);
  // 5. CB[bc][i][j] = C_i . B_j  (batched 256x256, K=128)  MFMA
  gemm_mfma<1><<<dim3(2, 2, 32), 256, 0, stream>>>(
      xbc + 4224, xbc + 4096, CBb, 256, 128, 4352, 4352, 256,
      256LL * 4352, 256LL * 4352, 65536LL);
  // 6. per-chunk end states (MFMA)
  states_mfma<<<dim3(32, 64), 256, 0, stream>>>(xbc, dt_sp, dAcs, BT, st);
  // 7. inter-chunk scan (in place: st becomes prev)
  scan_kernel<<<4096, 256, 0, stream>>>(st, dAcs);
  // 8. y_diag + y_off + Dp*x (MFMA) -> zx cols [4096,8192)
  ssm_y_mfma<<<dim3(32, 64), 256, 0, stream>>>(xbc, dt_sp, dAcs, CBb, st, Dp, zx);
  // 9. gated RMSNorm (in place)
  gated_rmsnorm<<<8192, 256, 0, stream>>>(zx, norm_w);
  // 10. W_out -> bf16 (into dead st region), then out_proj MFMA
  f32_to_bf16<<<4096, 256, 0, stream>>>(W_out, Wout_bf, 8388608LL);
  gemm_mfma<0><<<dim3(16, 64), 256, 0, stream>>>(
      zx + 4096, Wout_bf, out, 2048, 4096, 8576, 4096, 2048, 0, 0, 0);
}

// Round 12
// 964.564 us; speedup vs baseline: 6.0945x; 1.1504x over previous
//
#include <hip/hip_runtime.h>
#include <hip/hip_bf16.h>

typedef long long ll;
typedef unsigned int uint;
typedef unsigned short ushort;

typedef __bf16 bf16x8 __attribute__((ext_vector_type(8)));
typedef float f32x4 __attribute__((ext_vector_type(4)));

// Problem constants
// B=2, L=4096, D_MODEL=2048, D_INNER=4096, D_STATE=128, N_HEADS=64, D_HEAD=64
// CONV_DIM=4352, D_IN_PROJ=8512 (padded to 8576), CHUNK=256, 32 chunks
// Workspace layout identical to R11 (244 MiB, verified).

__device__ __forceinline__ float silu_f(float x) { return x / (1.0f + expf(-x)); }
__device__ __forceinline__ float softplus_f(float x) {
  return x > 20.0f ? x : log1pf(expf(x));
}
__device__ __forceinline__ float b2f(ushort u) {
  return __uint_as_float(((uint)u) << 16);
}
__device__ __forceinline__ ushort f2b(float f) {
  uint x = __float_as_uint(f);
  return (ushort)((x + 0x7FFFu + ((x >> 16) & 1u)) >> 16);
}
__device__ __forceinline__ uint pk2(float a, float b) {
  return (uint)f2b(a) | ((uint)f2b(b) << 16);
}
__device__ __forceinline__ void unpack8(uint4 u, float* f) {
  f[0] = b2f((ushort)(u.x & 0xffff)); f[1] = b2f((ushort)(u.x >> 16));
  f[2] = b2f((ushort)(u.y & 0xffff)); f[3] = b2f((ushort)(u.y >> 16));
  f[4] = b2f((ushort)(u.z & 0xffff)); f[5] = b2f((ushort)(u.z >> 16));
  f[6] = b2f((ushort)(u.w & 0xffff)); f[7] = b2f((ushort)(u.w >> 16));
}
__device__ __forceinline__ void unpack8u(uint4 u, ushort* e) {
  e[0] = (ushort)(u.x & 0xffff); e[1] = (ushort)(u.x >> 16);
  e[2] = (ushort)(u.y & 0xffff); e[3] = (ushort)(u.y >> 16);
  e[4] = (ushort)(u.z & 0xffff); e[5] = (ushort)(u.z >> 16);
  e[6] = (ushort)(u.w & 0xffff); e[7] = (ushort)(u.w >> 16);
}

#define GLDS16(g, l)                                                     \
  __builtin_amdgcn_global_load_lds(                                      \
      (const __attribute__((address_space(1))) void*)(g),                \
      (__attribute__((address_space(3))) void*)(l), 16, 0, 0)

// ---------------- f32 -> bf16 convert (8 elems/thread) ---------------------
__global__ __launch_bounds__(256) void f32_to_bf16(
    const float* __restrict__ in, ushort* __restrict__ out, ll n)
{
  ll i = ((ll)blockIdx.x * 256 + threadIdx.x) * 8;
  if (i + 8 > n) return;
  float4 a = *(const float4*)&in[i];
  float4 b = *(const float4*)&in[i + 4];
  ushort4 o0; o0.x = f2b(a.x); o0.y = f2b(a.y); o0.z = f2b(a.z); o0.w = f2b(a.w);
  ushort4 o1; o1.x = f2b(b.x); o1.y = f2b(b.y); o1.z = f2b(b.z); o1.w = f2b(b.w);
  *(ushort4*)&out[i] = o0;
  *(ushort4*)&out[i + 4] = o1;
}

// ---------------- 256x256 deep-pipelined bf16 MFMA GEMM --------------------
// C[M,N] = A[M,K] @ B[N,K]^T. 512 thr = 8 waves (2M x 4N), per-wave 128x64.
// BK=32 double-buffered 64KiB LDS; counted vmcnt(4) (loads in flight across
// raw s_barrier); LDS slot-XOR swizzle (linear gload_lds dest + inverse-
// swizzled global source + swizzled read); setprio around MFMA cluster;
// XCD-bijective block swizzle (requires gridDim.x % 8 == 0, K % 64 == 0,
// M % 256 == 0). Launched 1-D: nwg = gx * (M/256).
template <int CBF>  // 1: bf16 C, 0: f32 C
__global__ __launch_bounds__(512, 2) void gemm256(
    const ushort* __restrict__ A, const ushort* __restrict__ B, void* __restrict__ C,
    int Nreal, int Nstore, int K, int lda, int ldb, int ldc, int gx)
{
  __shared__ ushort lds[2][2][8192];   // [dbuf][A|B][256 rows x 32 cols] = 64 KiB
  const int t = threadIdx.x;
  const int lane = t & 63, w = t >> 6;
  const int wm = w >> 2, wn = w & 3;

  // T1: XCD-aware bijective swizzle (nwg % 8 == 0)
  const int nwg = gridDim.x;
  const int bid = blockIdx.x;
  const int swz = (bid & 7) * (nwg >> 3) + (bid >> 3);
  const int bm = (swz / gx) * 256, bn = (swz % gx) * 256;

  // staging: granule G = i*512 + t ; r = G>>2 ; s_phys = G&3 ;
  // logical slot loaded into s_phys is s_log = s_phys ^ (r&3)  (XOR involution)
  ll ga0, ga1, gb0, gb1;
  {
    int G0 = t, G1 = 512 + t;
    int r0 = G0 >> 2, r1 = G1 >> 2;
    int s0 = (G0 & 3) ^ (r0 & 3), s1 = (G1 & 3) ^ (r1 & 3);
    ga0 = (ll)(bm + r0) * lda + s0 * 8;
    ga1 = (ll)(bm + r1) * lda + s1 * 8;
    int br0 = bn + r0; if (br0 >= Nreal) br0 = Nreal - 1;
    int br1 = bn + r1; if (br1 >= Nreal) br1 = Nreal - 1;
    gb0 = (ll)br0 * ldb + s0 * 8;
    gb1 = (ll)br1 * ldb + s1 * 8;
  }
#define STAGE256(buf, k0) do {                        \
    GLDS16(A + ga0 + (k0), &lds[buf][0][t * 8]);      \
    GLDS16(A + ga1 + (k0), &lds[buf][0][t * 8 + 4096]); \
    GLDS16(B + gb0 + (k0), &lds[buf][1][t * 8]);      \
    GLDS16(B + gb1 + (k0), &lds[buf][1][t * 8 + 4096]); \
  } while (0)

  f32x4 acc[8][4];
#pragma unroll
  for (int m = 0; m < 8; ++m)
#pragma unroll
    for (int n = 0; n < 4; ++n) acc[m][n] = (f32x4){0.f, 0.f, 0.f, 0.f};

  // read offsets (ushorts): row r -> r*32 + (q ^ (r&3))*8, q = lane>>4
  const int fr = lane & 15, q = lane >> 4;
  int aoff[8], boff[4];
#pragma unroll
  for (int m = 0; m < 8; ++m) {
    int r = wm * 128 + m * 16 + fr;
    aoff[m] = r * 32 + ((q ^ (r & 3)) << 3);
  }
#pragma unroll
  for (int n = 0; n < 4; ++n) {
    int r = wn * 64 + n * 16 + fr;
    boff[n] = r * 32 + ((q ^ (r & 3)) << 3);
  }

  const int NT = K >> 5;   // K >= 64 assumed
  STAGE256(0, 0);
  STAGE256(1, 32);
  asm volatile("s_waitcnt vmcnt(4)" ::: "memory");
  asm volatile("s_barrier" ::: "memory");

  for (int kt = 0; kt < NT; ++kt) {
    const int cur = kt & 1;
    bf16x8 af[8], bf[4];
#pragma unroll
    for (int m = 0; m < 8; ++m) af[m] = *(const bf16x8*)&lds[cur][0][aoff[m]];
#pragma unroll
    for (int n = 0; n < 4; ++n) bf[n] = *(const bf16x8*)&lds[cur][1][boff[n]];
    __builtin_amdgcn_s_setprio(1);
#pragma unroll
    for (int m = 0; m < 8; ++m)
#pragma unroll
      for (int n = 0; n < 4; ++n)
        acc[m][n] = __builtin_amdgcn_mfma_f32_16x16x32_bf16(af[m], bf[n], acc[m][n], 0, 0, 0);
    __builtin_amdgcn_s_setprio(0);
    if (kt + 1 < NT) {
      asm volatile("s_barrier" ::: "memory");        // all waves done reading buf[cur]
      if (kt + 2 < NT) {
        STAGE256(cur, (kt + 2) * 32);                // refill; kt+1's 4 + these 4 in flight
        asm volatile("s_waitcnt vmcnt(4)" ::: "memory");  // wait kt+1 only
      } else {
        asm volatile("s_waitcnt vmcnt(0)" ::: "memory");  // tail drain
      }
      asm volatile("s_barrier" ::: "memory");        // buf[cur^1] ready for all
    }
  }
#undef STAGE256

  // epilogue: C/D layout col = lane&15, row = (lane>>4)*4 + j
  const int cr = (lane >> 4) << 2, cc = lane & 15;
#pragma unroll
  for (int m = 0; m < 8; ++m) {
#pragma unroll
    for (int n = 0; n < 4; ++n) {
#pragma unroll
      for (int j = 0; j < 4; ++j) {
        ll row = bm + wm * 128 + m * 16 + cr + j;
        int col = bn + wn * 64 + n * 16 + cc;
        if (col < Nstore) {
          if constexpr (CBF)
            ((ushort*)C)[row * ldc + col] = f2b(acc[m][n][j]);
          else
            ((float*)C)[row * ldc + col] = acc[m][n][j];
        }
      }
    }
  }
}

// ---------------- batched 128x128 MFMA GEMM (kept for CB) ------------------
template <int CBF>
__global__ __launch_bounds__(256) void gemm_mfma(
    const ushort* __restrict__ A, const ushort* __restrict__ B, void* __restrict__ C,
    int Nreal, int K, int lda, int ldb, int ldc,
    ll batchA, ll batchB, ll batchC)
{
  A += (ll)blockIdx.z * batchA;
  B += (ll)blockIdx.z * batchB;
  __shared__ ushort As[128 * 32];
  __shared__ ushort Bs[128 * 32];
  const int t = threadIdx.x;
  const int lane = t & 63, w = t >> 6;
  const int wr = w >> 1, wc = w & 1;
  const int bm = blockIdx.y * 128, bn = blockIdx.x * 128;

  const int srow = t >> 2, skc = (t & 3) << 3;
  const ll a0 = (ll)(bm + srow) * lda + skc;
  const ll a1 = (ll)(bm + 64 + srow) * lda + skc;
  int br0 = bn + srow;      if (br0 >= Nreal) br0 = Nreal - 1;
  int br1 = bn + 64 + srow; if (br1 >= Nreal) br1 = Nreal - 1;
  const ll b0 = (ll)br0 * ldb + skc;
  const ll b1 = (ll)br1 * ldb + skc;
  ushort* lA0 = As + t * 8;        ushort* lA1 = As + 2048 + t * 8;
  ushort* lB0 = Bs + t * 8;        ushort* lB1 = Bs + 2048 + t * 8;

  f32x4 acc[4][4];
#pragma unroll
  for (int m = 0; m < 4; ++m)
#pragma unroll
    for (int n = 0; n < 4; ++n) acc[m][n] = (f32x4){0.f, 0.f, 0.f, 0.f};

  const int fr = lane & 15;
  const int fk = (lane >> 4) << 3;

  for (int k0 = 0; k0 < K; k0 += 32) {
    GLDS16(A + a0 + k0, lA0);
    GLDS16(A + a1 + k0, lA1);
    GLDS16(B + b0 + k0, lB0);
    GLDS16(B + b1 + k0, lB1);
    __syncthreads();
    bf16x8 af[4], bf[4];
#pragma unroll
    for (int m = 0; m < 4; ++m)
      af[m] = *(const bf16x8*)&As[(wr * 64 + m * 16 + fr) * 32 + fk];
#pragma unroll
    for (int n = 0; n < 4; ++n)
      bf[n] = *(const bf16x8*)&Bs[(wc * 64 + n * 16 + fr) * 32 + fk];
#pragma unroll
    for (int m = 0; m < 4; ++m)
#pragma unroll
      for (int n = 0; n < 4; ++n)
        acc[m][n] = __builtin_amdgcn_mfma_f32_16x16x32_bf16(af[m], bf[n], acc[m][n], 0, 0, 0);
    __syncthreads();
  }

  const int cr = (lane >> 4) << 2, cc = lane & 15;
  const ll zc = (ll)blockIdx.z * batchC;
#pragma unroll
  for (int m = 0; m < 4; ++m) {
#pragma unroll
    for (int n = 0; n < 4; ++n) {
#pragma unroll
      for (int j = 0; j < 4; ++j) {
        ll row = bm + wr * 64 + m * 16 + cr + j;
        int col = bn + wc * 64 + n * 16 + cc;
        if constexpr (CBF)
          ((ushort*)C)[zc + row * ldc + col] = f2b(acc[m][n][j]);
        else
          ((float*)C)[zc + row * ldc + col] = acc[m][n][j];
      }
    }
  }
}

// ---------------- depthwise conv (width 4, causal) + bias + SiLU -----------
__global__ __launch_bounds__(256) void conv_silu(
    const ushort* __restrict__ zx, const float* __restrict__ cw,
    const float* __restrict__ cbias, ushort* __restrict__ out)
{
  ll tid = (ll)blockIdx.x * 256 + threadIdx.x;
  int ch4 = (int)(tid % 1088) << 2;
  ll bl = tid / 1088;
  int l = (int)(bl & 4095);
  ll rowbase = bl - l;
  float4 acc = *(const float4*)&cbias[ch4];
  float4 w0 = *(const float4*)&cw[(ch4 + 0) * 4];
  float4 w1 = *(const float4*)&cw[(ch4 + 1) * 4];
  float4 w2 = *(const float4*)&cw[(ch4 + 2) * 4];
  float4 w3 = *(const float4*)&cw[(ch4 + 3) * 4];
#define TAP(W, COMP)                                                               \
  { int llx = l + (W) - 3;                                                         \
    if (llx >= 0) {                                                                \
      ushort4 xv = *(const ushort4*)&zx[(rowbase + llx) * 8576 + 4096 + ch4];      \
      acc.x = fmaf(b2f(xv.x), w0.COMP, acc.x);                                     \
      acc.y = fmaf(b2f(xv.y), w1.COMP, acc.y);                                     \
      acc.z = fmaf(b2f(xv.z), w2.COMP, acc.z);                                     \
      acc.w = fmaf(b2f(xv.w), w3.COMP, acc.w); } }
  TAP(0, x) TAP(1, y) TAP(2, z) TAP(3, w)
#undef TAP
  ushort4 o;
  o.x = f2b(silu_f(acc.x)); o.y = f2b(silu_f(acc.y));
  o.z = f2b(silu_f(acc.z)); o.w = f2b(silu_f(acc.w));
  *(ushort4*)&out[bl * 4352 + ch4] = o;
}

// ---------------- dt softplus + per-chunk cumsum of dt*A -------------------
__global__ __launch_bounds__(256) void dt_cumsum(
    const ushort* __restrict__ zx, const float* __restrict__ dt_bias,
    const float* __restrict__ A_log, float* __restrict__ dt_sp,
    float* __restrict__ dA)
{
  __shared__ float sdt[256][64];
  const int bc = blockIdx.x;
  const int t = threadIdx.x;
#pragma unroll
  for (int q = 0; q < 16; ++q) {
    int ff = q * 256 + t;
    int i = ff >> 4;
    int h4 = (ff & 15) << 2;
    ushort4 v4 = *(const ushort4*)&zx[((ll)bc * 256 + i) * 8576 + 8448 + h4];
    float4 bb = *(const float4*)&dt_bias[h4];
    float4 v;
    v.x = softplus_f(b2f(v4.x) + bb.x); v.y = softplus_f(b2f(v4.y) + bb.y);
    v.z = softplus_f(b2f(v4.z) + bb.z); v.w = softplus_f(b2f(v4.w) + bb.w);
    *(float4*)&dt_sp[((ll)bc * 256 + i) * 64 + h4] = v;
    *(float4*)&sdt[i][h4] = v;
  }
  __syncthreads();
  if (t < 64) {
    const int h = t;
    const float Ah = -expf(A_log[h]);
    float run = 0.0f;
    for (int i = 0; i < 256; ++i) {
      run = fmaf(sdt[i][h], Ah, run);
      dA[((ll)bc * 256 + i) * 64 + h] = run;
    }
  }
}

// ---------------- transpose B cols of xbc -> BT[bc][n][s] ------------------
__global__ __launch_bounds__(256) void bt_transpose(
    const ushort* __restrict__ xbc, ushort* __restrict__ BT)
{
  const int bc = blockIdx.x;
  const int st0 = blockIdx.y * 64;
  const int nt0 = blockIdx.z * 64;
  const int t = threadIdx.x;
  const int s_loc = t & 63, strip = t >> 6;
  const int nb = nt0 + strip * 16;
  const ll row = (ll)(bc * 256 + st0 + s_loc) * 4352 + 4096 + nb;
  uint4 v0 = *(const uint4*)&xbc[row];
  uint4 v1 = *(const uint4*)&xbc[row + 8];
  ushort e[16];
  unpack8u(v0, e); unpack8u(v1, e + 8);
#pragma unroll
  for (int k = 0; k < 16; ++k)
    BT[((ll)bc * 128 + nb + k) * 256 + st0 + s_loc] = e[k];
}

// ---------------- per-chunk end states via MFMA: st[bc][h][p][n] -----------
__global__ __launch_bounds__(256) void states_mfma(
    const ushort* __restrict__ xbc, const float* __restrict__ dt_sp,
    const float* __restrict__ dA, const ushort* __restrict__ BT,
    ushort* __restrict__ st)
{
  const int bc = blockIdx.x, h = blockIdx.y;
  const int t = threadIdx.x, lane = t & 63, w = t >> 6;
  __shared__ ushort xwT[64][264];
  const float dAl = dA[((ll)bc * 256 + 255) * 64 + h];
  const float wloc = expf(dAl - dA[((ll)bc * 256 + t) * 64 + h]) *
                     dt_sp[((ll)bc * 256 + t) * 64 + h];
  {
    const ll xrow = ((ll)bc * 256 + t) * 4352 + h * 64;
#pragma unroll
    for (int g = 0; g < 8; ++g) {
      uint4 v = *(const uint4*)&xbc[xrow + g * 8];
      float f[8]; unpack8(v, f);
#pragma unroll
      for (int j = 0; j < 8; ++j)
        xwT[g * 8 + j][t] = f2b(f[j] * wloc);
    }
  }
  __syncthreads();

  const int fr = lane & 15, fk = (lane >> 4) << 3;
  f32x4 acc[4][2];
#pragma unroll
  for (int m = 0; m < 4; ++m)
#pragma unroll
    for (int n = 0; n < 2; ++n) acc[m][n] = (f32x4){0.f, 0.f, 0.f, 0.f};

  for (int s0 = 0; s0 < 256; s0 += 32) {
    bf16x8 af[4], bf[2];
#pragma unroll
    for (int m = 0; m < 4; ++m)
      af[m] = *(const bf16x8*)&xwT[m * 16 + fr][s0 + fk];
#pragma unroll
    for (int n = 0; n < 2; ++n)
      bf[n] = *(const bf16x8*)&BT[((ll)bc * 128 + w * 32 + n * 16 + fr) * 256 + s0 + fk];
#pragma unroll
    for (int m = 0; m < 4; ++m)
#pragma unroll
      for (int n = 0; n < 2; ++n)
        acc[m][n] = __builtin_amdgcn_mfma_f32_16x16x32_bf16(af[m], bf[n], acc[m][n], 0, 0, 0);
  }

  const int cr = (lane >> 4) << 2, cc = lane & 15;
  const ll base = ((ll)bc * 64 + h) * 8192;
#pragma unroll
  for (int m = 0; m < 4; ++m)
#pragma unroll
    for (int n = 0; n < 2; ++n)
#pragma unroll
      for (int j = 0; j < 4; ++j) {
        int p = m * 16 + cr + j;
        int nn = w * 32 + n * 16 + cc;
        st[base + p * 128 + nn] = f2b(acc[m][n][j]);
      }
}

// ---------------- inter-chunk scan, in place -------------------------------
__global__ __launch_bounds__(256) void scan_kernel(
    ushort* __restrict__ st, const float* __restrict__ dA)
{
  ll tid = (ll)blockIdx.x * 256 + threadIdx.x;
  int n = (int)(tid & 127);
  int p = (int)((tid >> 7) & 63);
  int h = (int)((tid >> 13) & 63);
  int b = (int)(tid >> 19);
  float s = 0.0f;
#pragma unroll
  for (int c = 0; c < 16; ++c) {
    int bc = b * 16 + c;
    float dec = expf(dA[((ll)bc * 256 + 255) * 64 + h]);
    ll idx = ((ll)bc * 64 + h) * 8192 + p * 128 + n;
    float tmp = b2f(st[idx]);
    st[idx] = f2b(s);
    s = fmaf(s, dec, tmp);
  }
}

// ---------------- y = y_diag + y_off + Dp*x via MFMA -----------------------
__global__ __launch_bounds__(256) void ssm_y_mfma(
    const ushort* __restrict__ xbc, const float* __restrict__ dt_sp,
    const float* __restrict__ dA, const ushort* __restrict__ CB,
    const ushort* __restrict__ prev, const float* __restrict__ Dp,
    ushort* __restrict__ zx)
{
  const int bc = blockIdx.x, h = blockIdx.y;
  const int t = threadIdx.x, lane = t & 63, w = t >> 6;
  __shared__ float sA[256], sdt[256];
  __shared__ ushort xT[64][264];
  __shared__ ushort pv[64][136];

  sA[t]  = dA[((ll)bc * 256 + t) * 64 + h];
  sdt[t] = dt_sp[((ll)bc * 256 + t) * 64 + h];
  {
    const ll xrow = ((ll)bc * 256 + t) * 4352 + h * 64;
#pragma unroll
    for (int g = 0; g < 8; ++g) {
      uint4 v = *(const uint4*)&xbc[xrow + g * 8];
      ushort e[8]; unpack8u(v, e);
#pragma unroll
      for (int j = 0; j < 8; ++j) xT[g * 8 + j][t] = e[j];
    }
  }
  {
    const int p = t >> 2, n0 = (t & 3) * 32;
    const ll pb = ((ll)bc * 64 + h) * 8192 + (ll)p * 128 + n0;
#pragma unroll
    for (int g = 0; g < 4; ++g)
      *(uint4*)&pv[p][n0 + g * 8] = *(const uint4*)&prev[pb + g * 8];
  }
  __syncthreads();

  const int fr = lane & 15, fk = (lane >> 4) << 3;
  float dAi[4], ei[4];
  int im[4];
#pragma unroll
  for (int m = 0; m < 4; ++m) {
    im[m] = w * 64 + m * 16 + fr;
    dAi[m] = sA[im[m]];
    ei[m] = __expf(dAi[m]);
  }

  f32x4 acc[4][4];
#pragma unroll
  for (int m = 0; m < 4; ++m)
#pragma unroll
    for (int n = 0; n < 4; ++n) acc[m][n] = (f32x4){0.f, 0.f, 0.f, 0.f};

  const int nsteps = 2 * w + 2;
  for (int js = 0; js < nsteps; ++js) {
    const int j0 = js * 32;
    bf16x8 bf[4];
#pragma unroll
    for (int n = 0; n < 4; ++n)
      bf[n] = *(const bf16x8*)&xT[n * 16 + fr][j0 + fk];
    bf16x8 af[4];
#pragma unroll
    for (int m = 0; m < 4; ++m) {
      uint4 cb4 = *(const uint4*)&CB[((ll)bc * 256 + im[m]) * 256 + j0 + fk];
      float cb[8]; unpack8(cb4, cb);
#pragma unroll
      for (int jj = 0; jj < 8; ++jj) {
        int j = j0 + fk + jj;
        float mv = cb[jj] * sdt[j] * __expf(dAi[m] - sA[j]);
        af[m][jj] = (__bf16)((j <= im[m]) ? mv : 0.0f);
      }
    }
#pragma unroll
    for (int m = 0; m < 4; ++m)
#pragma unroll
      for (int n = 0; n < 4; ++n)
        acc[m][n] = __builtin_amdgcn_mfma_f32_16x16x32_bf16(af[m], bf[n], acc[m][n], 0, 0, 0);
  }

  for (int ns = 0; ns < 4; ++ns) {
    const int n0 = ns * 32;
    bf16x8 bf[4];
#pragma unroll
    for (int n = 0; n < 4; ++n)
      bf[n] = *(const bf16x8*)&pv[n * 16 + fr][n0 + fk];
    bf16x8 af[4];
#pragma unroll
    for (int m = 0; m < 4; ++m) {
      uint4 cv4 = *(const uint4*)&xbc[((ll)bc * 256 + im[m]) * 4352 + 4224 + n0 + fk];
      float cv[8]; unpack8(cv4, cv);
#pragma unroll
      for (int jj = 0; jj < 8; ++jj)
        af[m][jj] = (__bf16)(cv[jj] * ei[m]);
    }
#pragma unroll
    for (int m = 0; m < 4; ++m)
#pragma unroll
      for (int n = 0; n < 4; ++n)
        acc[m][n] = __builtin_amdgcn_mfma_f32_16x16x32_bf16(af[m], bf[n], acc[m][n], 0, 0, 0);
  }

  const int cr = (lane >> 4) << 2, cc = lane & 15;
  const float dph = Dp[h];
#pragma unroll
  for (int m = 0; m < 4; ++m) {
#pragma unroll
    for (int n = 0; n < 4; ++n) {
#pragma unroll
      for (int j = 0; j < 4; ++j) {
        int i_loc = w * 64 + m * 16 + cr + j;
        int p = n * 16 + cc;
        float xval = b2f(xT[p][i_loc]);
        float val = acc[m][n][j] + dph * xval;
        zx[((ll)bc * 256 + i_loc) * 8576 + 4096 + h * 64 + p] = f2b(val);
      }
    }
  }
}

// ---------------- gated RMSNorm, in place on zx cols [4096,8192) -----------
__global__ __launch_bounds__(256) void gated_rmsnorm(
    ushort* __restrict__ zx, const float* __restrict__ norm_w)
{
  const ll row = blockIdx.x;
  ushort* zrow = zx + row * 8576;
  ushort* yrow = zrow + 4096;
  const int t = threadIdx.x;
  float g[16];
  float ss = 0.0f;
#pragma unroll
  for (int q = 0; q < 2; ++q) {
    int d = q * 2048 + t * 8;
    uint4 yv = *(const uint4*)&yrow[d];
    uint4 zv = *(const uint4*)&zrow[d];
    float yf[8], zf[8];
    unpack8(yv, yf);
    unpack8(zv, zf);
#pragma unroll
    for (int j = 0; j < 8; ++j) {
      float gv = yf[j] * silu_f(zf[j]);
      g[q * 8 + j] = gv;
      ss += gv * gv;
    }
  }
#pragma unroll
  for (int o = 32; o > 0; o >>= 1) ss += __shfl_xor(ss, o);
  __shared__ float red[4];
  if ((t & 63) == 0) red[t >> 6] = ss;
  __syncthreads();
  ss = red[0] + red[1] + red[2] + red[3];
  float scale = rsqrtf(ss * (1.0f / 4096.0f) + 1e-5f);
#pragma unroll
  for (int q = 0; q < 2; ++q) {
    int d = q * 2048 + t * 8;
    float4 w0 = *(const float4*)&norm_w[d];
    float4 w1 = *(const float4*)&norm_w[d + 4];
    uint4 o;
    o.x = pk2(g[q * 8 + 0] * scale * w0.x, g[q * 8 + 1] * scale * w0.y);
    o.y = pk2(g[q * 8 + 2] * scale * w0.z, g[q * 8 + 3] * scale * w0.w);
    o.z = pk2(g[q * 8 + 4] * scale * w1.x, g[q * 8 + 5] * scale * w1.y);
    o.w = pk2(g[q * 8 + 6] * scale * w1.z, g[q * 8 + 7] * scale * w1.w);
    *(uint4*)&yrow[d] = o;
  }
}

extern "C" void kernel_launch(void* const* d_in, const int* in_sizes, int n_in,
                              void* d_out, int out_size, void* d_ws, size_t ws_size,
                              hipStream_t stream) {
  const float* u       = (const float*)d_in[0];
  const float* W_in    = (const float*)d_in[1];
  const float* conv_w  = (const float*)d_in[2];
  const float* conv_b  = (const float*)d_in[3];
  const float* dt_bias = (const float*)d_in[4];
  const float* A_log   = (const float*)d_in[5];
  const float* Dp      = (const float*)d_in[6];
  const float* norm_w  = (const float*)d_in[7];
  const float* W_out   = (const float*)d_in[8];
  float* out = (float*)d_out;

  char* wsb = (char*)d_ws;
  ushort* zx      = (ushort*)wsb;                    // [8192][8576] bf16
  ushort* xbc     = (ushort*)(wsb + 140509184LL);    // [8192][4352] bf16
  ushort* u_bf    = xbc;                             // alias (dead after gemm1)
  ushort* Win_bf  = (ushort*)(wsb + 174063616LL);    // alias inside xbc region
  ushort* st      = (ushort*)(wsb + 211812352LL);    // [32][64][64][128] bf16
  ushort* Wout_bf = st;                              // alias (st dead after ssm_y)
  ushort* CBb     = (ushort*)(wsb + 245366784LL);
  float*  dt_sp   = (float*)(wsb + 249561088LL);
  float*  dAcs    = (float*)(wsb + 251658240LL);
  ushort* BT      = (ushort*)(wsb + 253755392LL);    // [32][128][256] bf16
  // total 255,852,544 B = 244 MiB (identical to R11)

  // 0. fp32 -> bf16 operand conversion
  f32_to_bf16<<<8192, 256, 0, stream>>>(u, u_bf, 16777216LL);
  f32_to_bf16<<<8512, 256, 0, stream>>>(W_in, Win_bf, 17432576LL);
  // 1. in_proj: zx = u @ W_in^T  [8192 x 8512(store-pad 8576), K=2048]
  //    grid: gx=34 col-tiles x 32 row-tiles = 1088 (%8==0)
  gemm256<1><<<1088, 512, 0, stream>>>(
      u_bf, Win_bf, zx, 8512, 8576, 2048, 2048, 2048, 8576, 34);
  // 2. causal conv + SiLU
  conv_silu<<<34816, 256, 0, stream>>>(zx, conv_w, conv_b, xbc);
  // 3. dt softplus + chunk cumsum
  dt_cumsum<<<32, 256, 0, stream>>>(zx, dt_bias, A_log, dt_sp, dAcs);
  // 4. B^T per chunk for states
  bt_transpose<<<dim3(32, 4, 2), 256, 0, stream>>>(xbc, BT);
  // 5. CB[bc][i][j] = C_i . B_j  (batched 256x256, K=128)
  gemm_mfma<1><<<dim3(2, 2, 32), 256, 0, stream>>>(
      xbc + 4224, xbc + 4096, CBb, 256, 128, 4352, 4352, 256,
      256LL * 4352, 256LL * 4352, 65536LL);
  // 6. per-chunk end states (MFMA)
  states_mfma<<<dim3(32, 64), 256, 0, stream>>>(xbc, dt_sp, dAcs, BT, st);
  // 7. inter-chunk scan (in place: st becomes prev)
  scan_kernel<<<4096, 256, 0, stream>>>(st, dAcs);
  // 8. y_diag + y_off + Dp*x (MFMA) -> zx cols [4096,8192)
  ssm_y_mfma<<<dim3(32, 64), 256, 0, stream>>>(xbc, dt_sp, dAcs, CBb, st, Dp, zx);
  // 9. gated RMSNorm (in place)
  gated_rmsnorm<<<8192, 256, 0, stream>>>(zx, norm_w);
  // 10. W_out -> bf16 (into dead st region), then out_proj
  f32_to_bf16<<<4096, 256, 0, stream>>>(W_out, Wout_bf, 8388608LL);
  //     out_proj: [8192 x 2048, K=4096]; grid 8x32 = 256 (%8==0)
  gemm256<0><<<256, 512, 0, stream>>>(
      zx + 4096, Wout_bf, out, 2048, 2048, 4096, 8576, 4096, 2048, 8);
}